// Round 6
// baseline (95.190 us; speedup 1.0000x reference)
//
#include <hip/hip_runtime.h>
#include <hip/hip_bf16.h>

typedef unsigned short ushort_t;
typedef unsigned int uint_t;
typedef __attribute__((ext_vector_type(8))) short s16x8;
typedef __attribute__((ext_vector_type(4))) float f32x4;
typedef __attribute__((ext_vector_type(4))) ushort_t u16x4;
typedef __attribute__((ext_vector_type(8))) ushort_t u16x8;

__device__ __forceinline__ ushort_t f2bf(float f) {
    uint_t u = __float_as_uint(f);
    uint_t r = (u + 0x7FFFu + ((u >> 16) & 1u)) >> 16;
    return (ushort_t)r;
}
__device__ __forceinline__ float bf2f(ushort_t u) {
    return __uint_as_float(((uint_t)u) << 16);
}
__device__ __forceinline__ s16x8 relu8(s16x8 v) {
    s16x8 r;
#pragma unroll
    for (int e = 0; e < 8; ++e) { short xv = v[e]; r[e] = (xv < 0) ? (short)0 : xv; }
    return r;
}

// zero xpTh (9,732,096 bytes = 608,256 uint4)
__global__ void zero_kernel(uint4* __restrict__ p) {
    int i = blockIdx.x * 256 + threadIdx.x;
    if (i < 608256) p[i] = make_uint4(0u, 0u, 0u, 0u);
}

// ---- prep: t1h[c][p], t2T[p][c], xpTh[s(4752)][c] (padded transpose, interior) ----
__global__ __launch_bounds__(256) void xtr_prep(const float* __restrict__ x,
                                                const float* __restrict__ p1,
                                                ushort_t* __restrict__ t1h,
                                                ushort_t* __restrict__ t2T,
                                                ushort_t* __restrict__ xpTh) {
    __shared__ float xs[64][65];
    __shared__ float p1s[64];
    const int y  = blockIdx.x;
    const int c0 = blockIdx.y * 64;
    const int n  = blockIdx.z;
    const int t  = threadIdx.x;
    if (t < 64) p1s[t] = p1[(c0 + t) * 64 + y];
#pragma unroll
    for (int cc = 0; cc < 4; ++cc) {
        int c = cc * 16 + (t >> 4);
        int px = (t & 15) * 4;
        float4 v = *(const float4*)(x + ((size_t)((n * 128 + c0 + c)) * 64 + y) * 64 + px);
        xs[c][px] = v.x; xs[c][px + 1] = v.y; xs[c][px + 2] = v.z; xs[c][px + 3] = v.w;
    }
    __syncthreads();
    {   // t1h natural layout
        int c = t >> 2, px0 = (t & 3) * 16;
        float pv = p1s[c];
        u16x8 o0, o1;
#pragma unroll
        for (int e = 0; e < 8; ++e) {
            o0[e] = f2bf(pv * xs[c][px0 + e]);
            o1[e] = f2bf(pv * xs[c][px0 + 8 + e]);
        }
        ushort_t* dst = t1h + (size_t)(n * 128 + c0 + c) * 4096 + y * 64 + px0;
        *(u16x8*)dst = o0;
        *(u16x8*)(dst + 8) = o1;
    }
    {   // transposed outputs: raw x -> xpTh (interior), t2 -> t2T
        int p = t >> 2, cx0 = (t & 3) * 16;
        u16x8 r0, r1, s0, s1;
#pragma unroll
        for (int e = 0; e < 8; ++e) {
            float v0 = xs[cx0 + e][p];
            float v1 = xs[cx0 + 8 + e][p];
            r0[e] = f2bf(v0);
            r1[e] = f2bf(v1);
            s0[e] = f2bf(v0 + p1s[cx0 + e] * v0);
            s1[e] = f2bf(v1 + p1s[cx0 + 8 + e] * v1);
        }
        size_t baseT = ((size_t)n * 4096 + y * 64 + p) * 128 + c0 + cx0;
        *(u16x8*)(t2T + baseT) = s0;
        *(u16x8*)(t2T + baseT + 8) = s1;
        size_t baseP = ((size_t)n * 4752 + (y + 1) * 72 + p + 3) * 128 + c0 + cx0;
        *(u16x8*)(xpTh + baseP) = r0;
        *(u16x8*)(xpTh + baseP + 8) = r1;
    }
}

// merged: wfc[g][tap][j][c32] = bf16(p10[...]) ; p7h = bf16(p7)
__global__ void wfcp_gen(const float* __restrict__ p10, const float* __restrict__ p7,
                         ushort_t* __restrict__ wfc, ushort_t* __restrict__ p7h) {
    int idx = blockIdx.x * 256 + threadIdx.x;
    if (idx < 86016) {
        int c32 = idx & 31;
        int j = (idx >> 5) & 31;
        int rest = idx >> 10;                   // g*21 + tap
        int tap = rest % 21, g = rest / 21;
        wfc[idx] = f2bf(p10[((32 * g + c32) * 21 + tap) * 32 + j]);
    } else if (idx < 86016 + 16384) {
        int i = idx - 86016;
        p7h[i] = f2bf(p7[i]);
    }
}

// ---- G[p][j] grouped 3x7 conv via MFMA: Gh[n][32g+j][p] ----
__global__ __launch_bounds__(256) void g_mfma(const ushort_t* __restrict__ xpTh,
                                              const ushort_t* __restrict__ wfc,
                                              ushort_t* __restrict__ Gh) {
    __shared__ ushort_t As[1024];
    __shared__ ushort_t Bs[8192];
    const int p0 = blockIdx.x * 256;
    const int g  = blockIdx.y;
    const int n  = blockIdx.z;
    const int tid = threadIdx.x;
    const int lane = tid & 63, wid = tid >> 6;
    const int q = lane >> 4, fr = lane & 15;
    const int y0 = p0 >> 6;
    const int syy = y0 + (tid >> 6);
    const int sxx = tid & 63;

    int aRd[2], bRd[4];
#pragma unroll
    for (int i = 0; i < 2; ++i) {
        int e = i * 16 + fr;
        aRd[i] = (e >> 1) * 64 + (((((e & 1) << 2) | q)) ^ ((e >> 1) & 7)) * 8;
    }
#pragma unroll
    for (int j = 0; j < 4; ++j) {
        int e = wid * 64 + j * 16 + fr;
        bRd[j] = (e >> 1) * 64 + (((((e & 1) << 2) | q)) ^ ((e >> 1) & 7)) * 8;
    }
    int bWr[4];
#pragma unroll
    for (int qq = 0; qq < 4; ++qq)
        bWr[qq] = (tid >> 1) * 64 + (((((tid & 1) << 2) | qq)) ^ ((tid >> 1) & 7)) * 8;
    int aWr = 0;
    if (tid < 128) {
        int e = tid >> 2, qq = tid & 3;
        aWr = (e >> 1) * 64 + (((((e & 1) << 2) | qq)) ^ ((e >> 1) & 7)) * 8;
    }
    const ushort_t* bSrcBase = xpTh + (size_t)n * 4752 * 128 + g * 32;

    f32x4 acc[2][4] = {};
    for (int tap = 0; tap < 21; ++tap) {
        int ki = tap / 7, kj = tap - ki * 7;
        const ushort_t* src = bSrcBase + (size_t)((syy + ki) * 72 + sxx + kj) * 128;
        u16x8 bv[4];
#pragma unroll
        for (int qq = 0; qq < 4; ++qq) bv[qq] = *(const u16x8*)(src + qq * 8);
        u16x8 av;
        if (tid < 128) av = *(const u16x8*)(wfc + (g * 21 + tap) * 1024 + tid * 8);
        __syncthreads();
#pragma unroll
        for (int qq = 0; qq < 4; ++qq) *(u16x8*)&Bs[bWr[qq]] = bv[qq];
        if (tid < 128) *(u16x8*)&As[aWr] = av;
        __syncthreads();
        s16x8 a[2], b[4];
#pragma unroll
        for (int i = 0; i < 2; ++i) a[i] = *(const s16x8*)&As[aRd[i]];
#pragma unroll
        for (int j = 0; j < 4; ++j) b[j] = *(const s16x8*)&Bs[bRd[j]];
#pragma unroll
        for (int i = 0; i < 2; ++i)
#pragma unroll
            for (int j = 0; j < 4; ++j)
                acc[i][j] = __builtin_amdgcn_mfma_f32_16x16x32_bf16(a[i], b[j], acc[i][j], 0, 0, 0);
    }
#pragma unroll
    for (int i = 0; i < 2; ++i) {
        int row = i * 16 + q * 4;
#pragma unroll
        for (int j = 0; j < 4; ++j) {
            int col = wid * 64 + j * 16 + fr;
            ushort_t* dst = Gh + ((size_t)n * 128 + 32 * g + row) * 4096 + p0 + col;
#pragma unroll
            for (int reg = 0; reg < 4; ++reg)
                dst[(size_t)reg * 4096] = f2bf(acc[i][j][reg]);
        }
    }
}

// ---- U partials: upart[(n,ks)][c][j] = sum_{p in chunk} t1h[c][p]*Gh[j][p] ----
__global__ __launch_bounds__(256) void u_mfma(const ushort_t* __restrict__ t1h,
                                              const ushort_t* __restrict__ Gh,
                                              float* __restrict__ upart) {
    __shared__ ushort_t As[8192];
    __shared__ ushort_t Bs[8192];
    const int ks = blockIdx.x;
    const int n  = blockIdx.y;
    const int kbase = ks * 512;
    const int tid = threadIdx.x;
    const int lane = tid & 63, wid = tid >> 6;
    const int wr = wid >> 1, wc = wid & 1;
    const ushort_t* aPtr[4];
    const ushort_t* bPtr[4];
    int off[4];
#pragma unroll
    for (int r = 0; r < 4; ++r) {
        int slot = r * 256 + tid;
        int row = slot >> 3, ch = slot & 7;
        off[r] = (row * 8 + (ch ^ (row & 7))) * 8;
        aPtr[r] = t1h + (size_t)(n * 128 + row) * 4096 + kbase + ch * 8;
        bPtr[r] = Gh  + (size_t)(n * 128 + row) * 4096 + kbase + ch * 8;
    }
    const int q = lane >> 4, fr = lane & 15;
    int aRd[2][4], bRd[2][4];
#pragma unroll
    for (int i = 0; i < 4; ++i) {
        int ra = wr * 64 + i * 16 + fr;
        int rb = wc * 64 + i * 16 + fr;
#pragma unroll
        for (int ks2 = 0; ks2 < 2; ++ks2) {
            aRd[ks2][i] = (ra * 8 + ((ks2 * 4 + q) ^ (ra & 7))) * 8;
            bRd[ks2][i] = (rb * 8 + ((ks2 * 4 + q) ^ (rb & 7))) * 8;
        }
    }
    f32x4 acc[4][4] = {};
    for (int t = 0; t < 8; ++t) {
        s16x8 av[4], bv[4];
#pragma unroll
        for (int r = 0; r < 4; ++r) {
            av[r] = *(const s16x8*)aPtr[r];
            bv[r] = *(const s16x8*)bPtr[r];
            aPtr[r] += 64;
            bPtr[r] += 64;
        }
        __syncthreads();
#pragma unroll
        for (int r = 0; r < 4; ++r) {
            *(s16x8*)&As[off[r]] = av[r];
            *(s16x8*)&Bs[off[r]] = bv[r];
        }
        __syncthreads();
#pragma unroll
        for (int ks2 = 0; ks2 < 2; ++ks2) {
            s16x8 a[4], b[4];
#pragma unroll
            for (int i = 0; i < 4; ++i) a[i] = *(const s16x8*)&As[aRd[ks2][i]];
#pragma unroll
            for (int i = 0; i < 4; ++i) b[i] = *(const s16x8*)&Bs[bRd[ks2][i]];
#pragma unroll
            for (int i = 0; i < 4; ++i)
#pragma unroll
                for (int j = 0; j < 4; ++j)
                    acc[i][j] = __builtin_amdgcn_mfma_f32_16x16x32_bf16(a[i], b[j], acc[i][j], 0, 0, 0);
        }
    }
#pragma unroll
    for (int i = 0; i < 4; ++i) {
        int row = wr * 64 + i * 16 + q * 4;
#pragma unroll
        for (int j = 0; j < 4; ++j) {
            int col = wc * 64 + j * 16 + fr;
            float* dp = upart + ((size_t)(n * 8 + ks) * 128 + row) * 128 + col;
#pragma unroll
            for (int reg = 0; reg < 4; ++reg)
                dp[(size_t)reg * 128] = acc[i][j][reg];
        }
    }
}

__global__ void ureduce_kernel(const float* __restrict__ upart, ushort_t* __restrict__ Uh) {
    int idx = blockIdx.x * 256 + threadIdx.x;   // < 131072
    int n = idx >> 14, rc = idx & 16383;
    float s = 0.0f;
#pragma unroll
    for (int k = 0; k < 8; ++k) s += upart[(size_t)((n * 8 + k) << 14) + rc];
    Uh[idx] = f2bf(s * 0.015625f);               // 1/64
}

// ---- fused: t7 GEMM + t13 GEMM + combined epilogue ----
// out = max(x - 0.2*sum_win(t7), scale * (Uh . t2T^T)).  grid (32 ptiles, 8 n)
__global__ __launch_bounds__(256) void out_fused(const ushort_t* __restrict__ p7h,
                                                 const ushort_t* __restrict__ xpTh,
                                                 const ushort_t* __restrict__ Uh,
                                                 const ushort_t* __restrict__ t2T,
                                                 const float* __restrict__ x,
                                                 float* __restrict__ out) {
    __shared__ ushort_t sh[18176];               // 36,352 B
    ushort_t* As = sh;
    ushort_t* Bs = sh + 8192;
    const int p0 = blockIdx.x * 128;
    const int n  = blockIdx.y;
    const int tid = threadIdx.x;
    const int lane = tid & 63, wid = tid >> 6;
    const int wr = wid >> 1, wc = wid & 1;
    const int q = lane >> 4, fr = lane & 15;

    int off[4], rowOf[4], chOf[4];
#pragma unroll
    for (int r = 0; r < 4; ++r) {
        int slot = r * 256 + tid;
        int row = slot >> 3, ch = slot & 7;
        rowOf[r] = row; chOf[r] = ch;
        off[r] = (row * 8 + (ch ^ (row & 7))) * 8;
    }
    int aRd[2][4], bRd[2][4];
#pragma unroll
    for (int i = 0; i < 4; ++i) {
        int ra = wr * 64 + i * 16 + fr;
        int rb = wc * 64 + i * 16 + fr;
#pragma unroll
        for (int ks = 0; ks < 2; ++ks) {
            aRd[ks][i] = (ra * 8 + ((ks * 4 + q) ^ (ra & 7))) * 8;
            bRd[ks][i] = (rb * 8 + ((ks * 4 + q) ^ (rb & 7))) * 8;
        }
    }

    // ---- phase 1: t7 = p7h . relu(xpT)^T ----
    f32x4 acc7[4][4] = {};
    {
        const ushort_t* aPtr[4];
        const ushort_t* bPtr[4];
#pragma unroll
        for (int r = 0; r < 4; ++r) {
            aPtr[r] = p7h + rowOf[r] * 128 + chOf[r] * 8;
            int prow = p0 + rowOf[r];
            int srow = ((prow >> 6) + 1) * 72 + (prow & 63) + 3;
            bPtr[r] = xpTh + ((size_t)n * 4752 + srow) * 128 + chOf[r] * 8;
        }
        for (int t = 0; t < 2; ++t) {
            s16x8 av[4], bv[4];
#pragma unroll
            for (int r = 0; r < 4; ++r) {
                av[r] = *(const s16x8*)aPtr[r];
                bv[r] = relu8(*(const s16x8*)bPtr[r]);
                aPtr[r] += 64;
                bPtr[r] += 64;
            }
            __syncthreads();
#pragma unroll
            for (int r = 0; r < 4; ++r) {
                *(s16x8*)&As[off[r]] = av[r];
                *(s16x8*)&Bs[off[r]] = bv[r];
            }
            __syncthreads();
#pragma unroll
            for (int ks = 0; ks < 2; ++ks) {
                s16x8 a[4], b[4];
#pragma unroll
                for (int i = 0; i < 4; ++i) a[i] = *(const s16x8*)&As[aRd[ks][i]];
#pragma unroll
                for (int i = 0; i < 4; ++i) b[i] = *(const s16x8*)&Bs[bRd[ks][i]];
#pragma unroll
                for (int i = 0; i < 4; ++i)
#pragma unroll
                    for (int j = 0; j < 4; ++j)
                        acc7[i][j] = __builtin_amdgcn_mfma_f32_16x16x32_bf16(a[i], b[j], acc7[i][j], 0, 0, 0);
            }
        }
    }
    // ---- phase 2: t13 = Uh . t2T^T ----
    f32x4 acc13[4][4] = {};
    {
        const ushort_t* aPtr[4];
        const ushort_t* bPtr[4];
#pragma unroll
        for (int r = 0; r < 4; ++r) {
            aPtr[r] = Uh + ((size_t)n * 128 + rowOf[r]) * 128 + chOf[r] * 8;
            bPtr[r] = t2T + ((size_t)n * 4096 + p0 + rowOf[r]) * 128 + chOf[r] * 8;
        }
        for (int t = 0; t < 2; ++t) {
            s16x8 av[4], bv[4];
#pragma unroll
            for (int r = 0; r < 4; ++r) {
                av[r] = *(const s16x8*)aPtr[r];
                bv[r] = *(const s16x8*)bPtr[r];
                aPtr[r] += 64;
                bPtr[r] += 64;
            }
            __syncthreads();
#pragma unroll
            for (int r = 0; r < 4; ++r) {
                *(s16x8*)&As[off[r]] = av[r];
                *(s16x8*)&Bs[off[r]] = bv[r];
            }
            __syncthreads();
#pragma unroll
            for (int ks = 0; ks < 2; ++ks) {
                s16x8 a[4], b[4];
#pragma unroll
                for (int i = 0; i < 4; ++i) a[i] = *(const s16x8*)&As[aRd[ks][i]];
#pragma unroll
                for (int i = 0; i < 4; ++i) b[i] = *(const s16x8*)&Bs[bRd[ks][i]];
#pragma unroll
                for (int i = 0; i < 4; ++i)
#pragma unroll
                    for (int j = 0; j < 4; ++j)
                        acc13[i][j] = __builtin_amdgcn_mfma_f32_16x16x32_bf16(a[i], b[j], acc13[i][j], 0, 0, 0);
            }
        }
    }
    // ---- epilogue: Cs (64x156 halo) for t7 window, Ds (64x128) for t13 ----
    ushort_t* Cs = sh;                    // 9984 ushorts
    ushort_t* Ds = sh + 9984;             // 8192 ushorts
    const float scale = 0.0192879257f;    // 1/sqrt(2688)
    for (int pass = 0; pass < 2; ++pass) {
        __syncthreads();
        for (int i2 = tid; i2 < 4992; i2 += 256) ((uint_t*)Cs)[i2] = 0u;
        __syncthreads();
        if (wr == pass) {
#pragma unroll
            for (int i = 0; i < 4; ++i) {
                int row = i * 16 + q * 4;
#pragma unroll
                for (int j = 0; j < 4; ++j) {
                    int col = wc * 64 + j * 16 + fr;
                    int cbase = (col >> 6) * 78 + 6 + (col & 63);
#pragma unroll
                    for (int reg = 0; reg < 4; ++reg) {
                        Cs[(row + reg) * 156 + cbase] = f2bf(acc7[i][j][reg]);
                        Ds[(row + reg) * 128 + col]   = f2bf(acc13[i][j][reg] * scale);
                    }
                }
            }
        }
        __syncthreads();
        for (int rep = 0; rep < 32; ++rep) {
            int flat = rep * 256 + tid;
            int ol = flat >> 7;
            int pcol = flat & 127;
            int half = pcol >> 6, xx = pcol & 63;
            float s = 0.0f;
#pragma unroll
            for (int jj = 0; jj < 5; ++jj)
                s += bf2f(Cs[ol * 156 + half * 78 + xx + 3 * jj]);
            float t13v = bf2f(Ds[ol * 128 + pcol]);
            size_t oi = ((size_t)(n * 128 + pass * 64 + ol)) * 4096 + p0 + pcol;
            out[oi] = fmaxf(x[oi] - 0.2f * s, t13v);
        }
    }
}

extern "C" void kernel_launch(void* const* d_in, const int* in_sizes, int n_in,
                              void* d_out, int out_size, void* d_ws, size_t ws_size,
                              hipStream_t stream) {
    const float* x   = (const float*)d_in[0];
    const float* p1  = (const float*)d_in[1];
    const float* p7  = (const float*)d_in[2];
    const float* p10 = (const float*)d_in[3];
    float* out = (float*)d_out;

    ushort_t* t1h  = (ushort_t*)d_ws;          // 4,194,304
    ushort_t* t2T  = t1h + 4194304;            // 4,194,304
    ushort_t* xpTh = t2T + 4194304;            // 4,866,048
    ushort_t* p7h  = xpTh + 4866048;           // 16,384
    ushort_t* Gh   = p7h + 16384;              // 4,194,304
    ushort_t* wfc  = Gh + 4194304;             // 86,016
    ushort_t* Uh   = wfc + 86016;              // 131,072
    float*    upart = (float*)(Uh + 131072);   // 1,048,576 f32

    zero_kernel<<<2376, 256, 0, stream>>>((uint4*)xpTh);
    xtr_prep<<<dim3(64, 2, 8), 256, 0, stream>>>(x, p1, t1h, t2T, xpTh);
    wfcp_gen<<<400, 256, 0, stream>>>(p10, p7, wfc, p7h);
    g_mfma<<<dim3(16, 4, 8), 256, 0, stream>>>(xpTh, wfc, Gh);
    u_mfma<<<dim3(8, 8), 256, 0, stream>>>(t1h, Gh, upart);
    ureduce_kernel<<<512, 256, 0, stream>>>(upart, Uh);
    out_fused<<<dim3(32, 8), 256, 0, stream>>>(p7h, xpTh, Uh, t2T, x, out);
}

// Round 7
// 71.203 us; speedup vs baseline: 1.3369x; 1.3369x over previous
//
#include <hip/hip_runtime.h>
#include <hip/hip_bf16.h>

typedef unsigned short ushort_t;
typedef unsigned int uint_t;
typedef __attribute__((ext_vector_type(8))) short s16x8;
typedef __attribute__((ext_vector_type(4))) float f32x4;
typedef __attribute__((ext_vector_type(4))) ushort_t u16x4;
typedef __attribute__((ext_vector_type(8))) ushort_t u16x8;

__device__ __forceinline__ ushort_t f2bf(float f) {
    uint_t u = __float_as_uint(f);
    uint_t r = (u + 0x7FFFu + ((u >> 16) & 1u)) >> 16;
    return (ushort_t)r;
}
__device__ __forceinline__ float bf2f(ushort_t u) {
    return __uint_as_float(((uint_t)u) << 16);
}
__device__ __forceinline__ s16x8 relu8(s16x8 v) {
    s16x8 r;
#pragma unroll
    for (int e = 0; e < 8; ++e) { short xv = v[e]; r[e] = (xv < 0) ? (short)0 : xv; }
    return r;
}

// zero xpTh (9,732,096 bytes = 608,256 uint4)
__global__ void zero_kernel(uint4* __restrict__ p) {
    int i = blockIdx.x * 256 + threadIdx.x;
    if (i < 608256) p[i] = make_uint4(0u, 0u, 0u, 0u);
}

// ---- prep: t1h[c][p], t2T[p][c], xpTh[s(4752)][c] (padded transpose, interior) ----
__global__ __launch_bounds__(256) void xtr_prep(const float* __restrict__ x,
                                                const float* __restrict__ p1,
                                                ushort_t* __restrict__ t1h,
                                                ushort_t* __restrict__ t2T,
                                                ushort_t* __restrict__ xpTh) {
    __shared__ float xs[64][65];
    __shared__ float p1s[64];
    const int y  = blockIdx.x;
    const int c0 = blockIdx.y * 64;
    const int n  = blockIdx.z;
    const int t  = threadIdx.x;
    if (t < 64) p1s[t] = p1[(c0 + t) * 64 + y];
#pragma unroll
    for (int cc = 0; cc < 4; ++cc) {
        int c = cc * 16 + (t >> 4);
        int px = (t & 15) * 4;
        float4 v = *(const float4*)(x + ((size_t)((n * 128 + c0 + c)) * 64 + y) * 64 + px);
        xs[c][px] = v.x; xs[c][px + 1] = v.y; xs[c][px + 2] = v.z; xs[c][px + 3] = v.w;
    }
    __syncthreads();
    {   // t1h natural layout
        int c = t >> 2, px0 = (t & 3) * 16;
        float pv = p1s[c];
        u16x8 o0, o1;
#pragma unroll
        for (int e = 0; e < 8; ++e) {
            o0[e] = f2bf(pv * xs[c][px0 + e]);
            o1[e] = f2bf(pv * xs[c][px0 + 8 + e]);
        }
        ushort_t* dst = t1h + (size_t)(n * 128 + c0 + c) * 4096 + y * 64 + px0;
        *(u16x8*)dst = o0;
        *(u16x8*)(dst + 8) = o1;
    }
    {   // transposed outputs: raw x -> xpTh (interior), t2 -> t2T
        int p = t >> 2, cx0 = (t & 3) * 16;
        u16x8 r0, r1, s0, s1;
#pragma unroll
        for (int e = 0; e < 8; ++e) {
            float v0 = xs[cx0 + e][p];
            float v1 = xs[cx0 + 8 + e][p];
            r0[e] = f2bf(v0);
            r1[e] = f2bf(v1);
            s0[e] = f2bf(v0 + p1s[cx0 + e] * v0);
            s1[e] = f2bf(v1 + p1s[cx0 + 8 + e] * v1);
        }
        size_t baseT = ((size_t)n * 4096 + y * 64 + p) * 128 + c0 + cx0;
        *(u16x8*)(t2T + baseT) = s0;
        *(u16x8*)(t2T + baseT + 8) = s1;
        size_t baseP = ((size_t)n * 4752 + (y + 1) * 72 + p + 3) * 128 + c0 + cx0;
        *(u16x8*)(xpTh + baseP) = r0;
        *(u16x8*)(xpTh + baseP + 8) = r1;
    }
}

// merged: wfc[g][tap][j][c32] = bf16(p10[...]) ; p7h = bf16(p7)
__global__ void wfcp_gen(const float* __restrict__ p10, const float* __restrict__ p7,
                         ushort_t* __restrict__ wfc, ushort_t* __restrict__ p7h) {
    int idx = blockIdx.x * 256 + threadIdx.x;
    if (idx < 86016) {
        int c32 = idx & 31;
        int j = (idx >> 5) & 31;
        int rest = idx >> 10;                   // g*21 + tap
        int tap = rest % 21, g = rest / 21;
        wfc[idx] = f2bf(p10[((32 * g + c32) * 21 + tap) * 32 + j]);
    } else if (idx < 86016 + 16384) {
        int i = idx - 86016;
        p7h[i] = f2bf(p7[i]);
    }
}

// ---- G[p][j] grouped 3x7 conv via MFMA, stage-once: Gh[n][32g+j][p] ----
// grid (16 ptiles, 4 g, 8 n), 256 thr. LDS slab = 6 rows x 72 cols x 32 ch.
// chunk swizzle: 16B chunk qq of (rr,cc) stored at chunk' = qq ^ ((cc>>1)&3).
__global__ __launch_bounds__(256) void g_mfma(const ushort_t* __restrict__ xpTh,
                                              const ushort_t* __restrict__ wfc,
                                              ushort_t* __restrict__ Gh) {
    __shared__ ushort_t Ts[6 * 72 * 32];        // 27,648 B
    const int p0 = blockIdx.x * 256;
    const int g  = blockIdx.y;
    const int n  = blockIdx.z;
    const int tid = threadIdx.x;
    const int lane = tid & 63, wid = tid >> 6;
    const int q = lane >> 4, fr = lane & 15;
    const int y0 = p0 >> 6;                     // padded row base

    // stage 6x72x(4 chunks of 8ch): 1728 chunks, 256 thr -> 7 iters (guarded)
    const ushort_t* src = xpTh + ((size_t)n * 4752 + y0 * 72) * 128 + g * 32;
    for (int flat = tid; flat < 1728; flat += 256) {
        int qq = flat & 3;
        int cc = (flat >> 2) % 72;
        int rr = (flat >> 2) / 72;
        u16x8 v = *(const u16x8*)(src + ((size_t)rr * 72 + cc) * 128 + qq * 8);
        *(u16x8*)&Ts[(rr * 72 + cc) * 32 + ((qq ^ ((cc >> 1) & 3)) * 8)] = v;
    }
    __syncthreads();

    const ushort_t* wbase = wfc + (size_t)g * 21 * 1024 + fr * 32 + q * 8;
    f32x4 acc[2][4] = {};
    for (int tap = 0; tap < 21; ++tap) {
        const int ki = tap / 7, kj = tap - ki * 7;
        s16x8 a[2], b[4];
#pragma unroll
        for (int i = 0; i < 2; ++i)
            a[i] = *(const s16x8*)(wbase + tap * 1024 + i * 16 * 32);
#pragma unroll
        for (int jj = 0; jj < 4; ++jj) {
            int col = wid * 64 + jj * 16 + fr;
            int rr = (col >> 6) + ki;
            int cc = (col & 63) + kj;
            b[jj] = *(const s16x8*)&Ts[(rr * 72 + cc) * 32 + ((q ^ ((cc >> 1) & 3)) * 8)];
        }
#pragma unroll
        for (int i = 0; i < 2; ++i)
#pragma unroll
            for (int jj = 0; jj < 4; ++jj)
                acc[i][jj] = __builtin_amdgcn_mfma_f32_16x16x32_bf16(a[i], b[jj], acc[i][jj], 0, 0, 0);
    }
#pragma unroll
    for (int i = 0; i < 2; ++i) {
        int row = i * 16 + q * 4;
#pragma unroll
        for (int jj = 0; jj < 4; ++jj) {
            int col = wid * 64 + jj * 16 + fr;
            ushort_t* dst = Gh + ((size_t)n * 128 + 32 * g + row) * 4096 + p0 + col;
#pragma unroll
            for (int reg = 0; reg < 4; ++reg)
                dst[(size_t)reg * 4096] = f2bf(acc[i][jj][reg]);
        }
    }
}

// ---- fused t7 (MFMA, relu-on-load from xpTh) + t12 epilogue ----
__global__ __launch_bounds__(256) void t7t12_mfma(const ushort_t* __restrict__ p7h,
                                                  const ushort_t* __restrict__ xpTh,
                                                  const float* __restrict__ x,
                                                  float* __restrict__ out) {
    __shared__ ushort_t sh[16384];
    ushort_t* As = sh;
    ushort_t* Bs = sh + 8192;
    const int p0 = blockIdx.x * 128;
    const int n  = blockIdx.y;
    const int tid = threadIdx.x;
    const int lane = tid & 63, wid = tid >> 6;
    const int wr = wid >> 1, wc = wid & 1;

    const ushort_t* aPtr[4];
    const ushort_t* bPtr[4];
    int off[4];
#pragma unroll
    for (int r = 0; r < 4; ++r) {
        int slot = r * 256 + tid;
        int row = slot >> 3, ch = slot & 7;
        off[r] = (row * 8 + (ch ^ (row & 7))) * 8;
        aPtr[r] = p7h + row * 128 + ch * 8;
        int prow = p0 + row;
        int srow = ((prow >> 6) + 1) * 72 + (prow & 63) + 3;
        bPtr[r] = xpTh + ((size_t)n * 4752 + srow) * 128 + ch * 8;
    }
    const int q = lane >> 4, fr = lane & 15;
    int aRd[2][4], bRd[2][4];
#pragma unroll
    for (int i = 0; i < 4; ++i) {
        int ra = wr * 64 + i * 16 + fr;
        int rb = wc * 64 + i * 16 + fr;
#pragma unroll
        for (int ks = 0; ks < 2; ++ks) {
            aRd[ks][i] = (ra * 8 + ((ks * 4 + q) ^ (ra & 7))) * 8;
            bRd[ks][i] = (rb * 8 + ((ks * 4 + q) ^ (rb & 7))) * 8;
        }
    }
    f32x4 acc[4][4] = {};
    for (int t = 0; t < 2; ++t) {
        s16x8 av[4], bv[4];
#pragma unroll
        for (int r = 0; r < 4; ++r) {
            av[r] = *(const s16x8*)aPtr[r];
            bv[r] = relu8(*(const s16x8*)bPtr[r]);
            aPtr[r] += 64;
            bPtr[r] += 64;
        }
        __syncthreads();
#pragma unroll
        for (int r = 0; r < 4; ++r) {
            *(s16x8*)&As[off[r]] = av[r];
            *(s16x8*)&Bs[off[r]] = bv[r];
        }
        __syncthreads();
#pragma unroll
        for (int ks = 0; ks < 2; ++ks) {
            s16x8 a[4], b[4];
#pragma unroll
            for (int i = 0; i < 4; ++i) a[i] = *(const s16x8*)&As[aRd[ks][i]];
#pragma unroll
            for (int i = 0; i < 4; ++i) b[i] = *(const s16x8*)&Bs[bRd[ks][i]];
#pragma unroll
            for (int i = 0; i < 4; ++i)
#pragma unroll
                for (int j = 0; j < 4; ++j)
                    acc[i][j] = __builtin_amdgcn_mfma_f32_16x16x32_bf16(a[i], b[j], acc[i][j], 0, 0, 0);
        }
    }
    // t12 epilogue
    ushort_t* Cs = sh;
    for (int pass = 0; pass < 2; ++pass) {
        __syncthreads();
        for (int i2 = tid; i2 < 4992; i2 += 256) ((uint_t*)Cs)[i2] = 0u;
        __syncthreads();
        if (wr == pass) {
#pragma unroll
            for (int i = 0; i < 4; ++i) {
                int row = i * 16 + q * 4;
#pragma unroll
                for (int j = 0; j < 4; ++j) {
                    int col = wc * 64 + j * 16 + fr;
                    int cbase = (col >> 6) * 78 + 6 + (col & 63);
#pragma unroll
                    for (int reg = 0; reg < 4; ++reg)
                        Cs[(row + reg) * 156 + cbase] = f2bf(acc[i][j][reg]);
                }
            }
        }
        __syncthreads();
        for (int rep = 0; rep < 32; ++rep) {
            int flat = rep * 256 + tid;
            int ol = flat >> 7;
            int pcol = flat & 127;
            int half = pcol >> 6, xx = pcol & 63;
            float s = 0.0f;
#pragma unroll
            for (int jj = 0; jj < 5; ++jj)
                s += bf2f(Cs[ol * 156 + half * 78 + xx + 3 * jj]);
            size_t oi = ((size_t)(n * 128 + pass * 64 + ol)) * 4096 + p0 + pcol;
            out[oi] = x[oi] - 0.2f * s;
        }
    }
}

// ---- U partials: upart[(n,ks)][c][j] = sum_{p in chunk} t1h[c][p]*Gh[j][p] ----
__global__ __launch_bounds__(256) void u_mfma(const ushort_t* __restrict__ t1h,
                                              const ushort_t* __restrict__ Gh,
                                              float* __restrict__ upart) {
    __shared__ ushort_t As[8192];
    __shared__ ushort_t Bs[8192];
    const int ks = blockIdx.x;
    const int n  = blockIdx.y;
    const int kbase = ks * 512;
    const int tid = threadIdx.x;
    const int lane = tid & 63, wid = tid >> 6;
    const int wr = wid >> 1, wc = wid & 1;
    const ushort_t* aPtr[4];
    const ushort_t* bPtr[4];
    int off[4];
#pragma unroll
    for (int r = 0; r < 4; ++r) {
        int slot = r * 256 + tid;
        int row = slot >> 3, ch = slot & 7;
        off[r] = (row * 8 + (ch ^ (row & 7))) * 8;
        aPtr[r] = t1h + (size_t)(n * 128 + row) * 4096 + kbase + ch * 8;
        bPtr[r] = Gh  + (size_t)(n * 128 + row) * 4096 + kbase + ch * 8;
    }
    const int q = lane >> 4, fr = lane & 15;
    int aRd[2][4], bRd[2][4];
#pragma unroll
    for (int i = 0; i < 4; ++i) {
        int ra = wr * 64 + i * 16 + fr;
        int rb = wc * 64 + i * 16 + fr;
#pragma unroll
        for (int ks2 = 0; ks2 < 2; ++ks2) {
            aRd[ks2][i] = (ra * 8 + ((ks2 * 4 + q) ^ (ra & 7))) * 8;
            bRd[ks2][i] = (rb * 8 + ((ks2 * 4 + q) ^ (rb & 7))) * 8;
        }
    }
    f32x4 acc[4][4] = {};
    for (int t = 0; t < 8; ++t) {
        s16x8 av[4], bv[4];
#pragma unroll
        for (int r = 0; r < 4; ++r) {
            av[r] = *(const s16x8*)aPtr[r];
            bv[r] = *(const s16x8*)bPtr[r];
            aPtr[r] += 64;
            bPtr[r] += 64;
        }
        __syncthreads();
#pragma unroll
        for (int r = 0; r < 4; ++r) {
            *(s16x8*)&As[off[r]] = av[r];
            *(s16x8*)&Bs[off[r]] = bv[r];
        }
        __syncthreads();
#pragma unroll
        for (int ks2 = 0; ks2 < 2; ++ks2) {
            s16x8 a[4], b[4];
#pragma unroll
            for (int i = 0; i < 4; ++i) a[i] = *(const s16x8*)&As[aRd[ks2][i]];
#pragma unroll
            for (int i = 0; i < 4; ++i) b[i] = *(const s16x8*)&Bs[bRd[ks2][i]];
#pragma unroll
            for (int i = 0; i < 4; ++i)
#pragma unroll
                for (int j = 0; j < 4; ++j)
                    acc[i][j] = __builtin_amdgcn_mfma_f32_16x16x32_bf16(a[i], b[j], acc[i][j], 0, 0, 0);
        }
    }
#pragma unroll
    for (int i = 0; i < 4; ++i) {
        int row = wr * 64 + i * 16 + q * 4;
#pragma unroll
        for (int j = 0; j < 4; ++j) {
            int col = wc * 64 + j * 16 + fr;
            float* dp = upart + ((size_t)(n * 8 + ks) * 128 + row) * 128 + col;
#pragma unroll
            for (int reg = 0; reg < 4; ++reg)
                dp[(size_t)reg * 128] = acc[i][j][reg];
        }
    }
}

__global__ void ureduce_kernel(const float* __restrict__ upart, ushort_t* __restrict__ Uh) {
    int idx = blockIdx.x * 256 + threadIdx.x;   // < 131072
    int n = idx >> 14, rc = idx & 16383;
    float s = 0.0f;
#pragma unroll
    for (int k = 0; k < 8; ++k) s += upart[(size_t)((n * 8 + k) << 14) + rc];
    Uh[idx] = f2bf(s * 0.015625f);               // 1/64
}

// ---- t13: out = max(out, scale * Uh . t2T^T). grid (32 ptiles, 8 n) ----
__global__ __launch_bounds__(256) void t13_mfma(const ushort_t* __restrict__ Uh,
                                                const ushort_t* __restrict__ t2T,
                                                float* __restrict__ out) {
    __shared__ ushort_t As[8192];
    __shared__ ushort_t Bs[8192];
    const int p0 = blockIdx.x * 128;
    const int n  = blockIdx.y;
    const int tid = threadIdx.x;
    const int lane = tid & 63, wid = tid >> 6;
    const int wr = wid >> 1, wc = wid & 1;
    const ushort_t* aPtr[4];
    const ushort_t* bPtr[4];
    int off[4];
#pragma unroll
    for (int r = 0; r < 4; ++r) {
        int slot = r * 256 + tid;
        int row = slot >> 3, ch = slot & 7;
        off[r] = (row * 8 + (ch ^ (row & 7))) * 8;
        aPtr[r] = Uh + ((size_t)n * 128 + row) * 128 + ch * 8;
        bPtr[r] = t2T + ((size_t)n * 4096 + p0 + row) * 128 + ch * 8;
    }
    const int q = lane >> 4, fr = lane & 15;
    int aRd[2][4], bRd[2][4];
#pragma unroll
    for (int i = 0; i < 4; ++i) {
        int ra = wr * 64 + i * 16 + fr;
        int rb = wc * 64 + i * 16 + fr;
#pragma unroll
        for (int ks = 0; ks < 2; ++ks) {
            aRd[ks][i] = (ra * 8 + ((ks * 4 + q) ^ (ra & 7))) * 8;
            bRd[ks][i] = (rb * 8 + ((ks * 4 + q) ^ (rb & 7))) * 8;
        }
    }
    f32x4 acc[4][4] = {};
    for (int t = 0; t < 2; ++t) {
        s16x8 av[4], bv[4];
#pragma unroll
        for (int r = 0; r < 4; ++r) {
            av[r] = *(const s16x8*)aPtr[r];
            bv[r] = *(const s16x8*)bPtr[r];
            aPtr[r] += 64;
            bPtr[r] += 64;
        }
        __syncthreads();
#pragma unroll
        for (int r = 0; r < 4; ++r) {
            *(s16x8*)&As[off[r]] = av[r];
            *(s16x8*)&Bs[off[r]] = bv[r];
        }
        __syncthreads();
#pragma unroll
        for (int ks = 0; ks < 2; ++ks) {
            s16x8 a[4], b[4];
#pragma unroll
            for (int i = 0; i < 4; ++i) a[i] = *(const s16x8*)&As[aRd[ks][i]];
#pragma unroll
            for (int i = 0; i < 4; ++i) b[i] = *(const s16x8*)&Bs[bRd[ks][i]];
#pragma unroll
            for (int i = 0; i < 4; ++i)
#pragma unroll
                for (int j = 0; j < 4; ++j)
                    acc[i][j] = __builtin_amdgcn_mfma_f32_16x16x32_bf16(a[i], b[j], acc[i][j], 0, 0, 0);
        }
    }
    const float scale = 0.0192879257f;   // 1/sqrt(2688)
#pragma unroll
    for (int i = 0; i < 4; ++i) {
        int row = wr * 64 + i * 16 + q * 4;
#pragma unroll
        for (int j = 0; j < 4; ++j) {
            int col = wc * 64 + j * 16 + fr;
#pragma unroll
            for (int reg = 0; reg < 4; ++reg) {
                size_t oi = ((size_t)(n * 128 + row + reg)) * 4096 + p0 + col;
                out[oi] = fmaxf(out[oi], acc[i][j][reg] * scale);
            }
        }
    }
}

extern "C" void kernel_launch(void* const* d_in, const int* in_sizes, int n_in,
                              void* d_out, int out_size, void* d_ws, size_t ws_size,
                              hipStream_t stream) {
    const float* x   = (const float*)d_in[0];
    const float* p1  = (const float*)d_in[1];
    const float* p7  = (const float*)d_in[2];
    const float* p10 = (const float*)d_in[3];
    float* out = (float*)d_out;

    ushort_t* t1h  = (ushort_t*)d_ws;          // 4,194,304
    ushort_t* t2T  = t1h + 4194304;            // 4,194,304
    ushort_t* xpTh = t2T + 4194304;            // 4,866,048
    ushort_t* p7h  = xpTh + 4866048;           // 16,384
    ushort_t* Gh   = p7h + 16384;              // 4,194,304
    ushort_t* wfc  = Gh + 4194304;             // 86,016
    ushort_t* Uh   = wfc + 86016;              // 131,072
    float*    upart = (float*)(Uh + 131072);   // 1,048,576 f32

    zero_kernel<<<2376, 256, 0, stream>>>((uint4*)xpTh);
    xtr_prep<<<dim3(64, 2, 8), 256, 0, stream>>>(x, p1, t1h, t2T, xpTh);
    wfcp_gen<<<400, 256, 0, stream>>>(p10, p7, wfc, p7h);
    g_mfma<<<dim3(16, 4, 8), 256, 0, stream>>>(xpTh, wfc, Gh);
    t7t12_mfma<<<dim3(32, 8), 256, 0, stream>>>(p7h, xpTh, x, out);
    u_mfma<<<dim3(8, 8), 256, 0, stream>>>(t1h, Gh, upart);
    ureduce_kernel<<<512, 256, 0, stream>>>(upart, Uh);
    t13_mfma<<<dim3(32, 8), 256, 0, stream>>>(Uh, t2T, out);
}

// Round 8
// 62.871 us; speedup vs baseline: 1.5140x; 1.1325x over previous
//
#include <hip/hip_runtime.h>
#include <hip/hip_bf16.h>

typedef unsigned short ushort_t;
typedef unsigned int uint_t;
typedef __attribute__((ext_vector_type(8))) short s16x8;
typedef __attribute__((ext_vector_type(4))) float f32x4;
typedef __attribute__((ext_vector_type(4))) ushort_t u16x4;
typedef __attribute__((ext_vector_type(8))) ushort_t u16x8;

__device__ __forceinline__ ushort_t f2bf(float f) {
    uint_t u = __float_as_uint(f);
    uint_t r = (u + 0x7FFFu + ((u >> 16) & 1u)) >> 16;
    return (ushort_t)r;
}
__device__ __forceinline__ float bf2f(ushort_t u) {
    return __uint_as_float(((uint_t)u) << 16);
}
__device__ __forceinline__ s16x8 relu8(s16x8 v) {
    s16x8 r;
#pragma unroll
    for (int e = 0; e < 8; ++e) { short xv = v[e]; r[e] = (xv < 0) ? (short)0 : xv; }
    return r;
}

// ---- merged misc prep: xpTh border zero + wfc gen + p7h cast ----
// items: 83968 border u16x8-chunks | 86016 wfc | 16384 p7h  => 186368 flat
__global__ void prep_misc(const float* __restrict__ p10, const float* __restrict__ p7,
                          ushort_t* __restrict__ xpTh, ushort_t* __restrict__ wfc,
                          ushort_t* __restrict__ p7h) {
    int idx = blockIdx.x * 256 + threadIdx.x;
    if (idx < 83968) {
        // border zero: n (8) x slot (656) x chunk (16)
        int chunk = idx & 15;
        int rest  = idx >> 4;             // n*656 + s
        int n = rest / 656;
        int s = rest - n * 656;
        int yy, xx;
        if (s < 144) { yy = (s < 72) ? 0 : 65; xx = s % 72; }
        else { int s2 = s - 144; yy = (s2 >> 3) + 1; int k = s2 & 7; xx = (k < 3) ? k : k + 64; }
        u16x8 z = {};
        *(u16x8*)(xpTh + ((size_t)n * 4752 + yy * 72 + xx) * 128 + chunk * 8) = z;
    } else if (idx < 83968 + 86016) {
        int i = idx - 83968;
        int c32 = i & 31;
        int j = (i >> 5) & 31;
        int rest = i >> 10;               // g*21 + tap
        int tap = rest % 21, g = rest / 21;
        wfc[i] = f2bf(p10[((32 * g + c32) * 21 + tap) * 32 + j]);
    } else if (idx < 83968 + 86016 + 16384) {
        int i = idx - 83968 - 86016;
        p7h[i] = f2bf(p7[i]);
    }
}

// ---- prep: t1h[c][p], t2T[p][c], xpTh[s(4752)][c] (padded transpose, interior) ----
__global__ __launch_bounds__(256) void xtr_prep(const float* __restrict__ x,
                                                const float* __restrict__ p1,
                                                ushort_t* __restrict__ t1h,
                                                ushort_t* __restrict__ t2T,
                                                ushort_t* __restrict__ xpTh) {
    __shared__ float xs[64][65];
    __shared__ float p1s[64];
    const int y  = blockIdx.x;
    const int c0 = blockIdx.y * 64;
    const int n  = blockIdx.z;
    const int t  = threadIdx.x;
    if (t < 64) p1s[t] = p1[(c0 + t) * 64 + y];
#pragma unroll
    for (int cc = 0; cc < 4; ++cc) {
        int c = cc * 16 + (t >> 4);
        int px = (t & 15) * 4;
        float4 v = *(const float4*)(x + ((size_t)((n * 128 + c0 + c)) * 64 + y) * 64 + px);
        xs[c][px] = v.x; xs[c][px + 1] = v.y; xs[c][px + 2] = v.z; xs[c][px + 3] = v.w;
    }
    __syncthreads();
    {   // t1h natural layout
        int c = t >> 2, px0 = (t & 3) * 16;
        float pv = p1s[c];
        u16x8 o0, o1;
#pragma unroll
        for (int e = 0; e < 8; ++e) {
            o0[e] = f2bf(pv * xs[c][px0 + e]);
            o1[e] = f2bf(pv * xs[c][px0 + 8 + e]);
        }
        ushort_t* dst = t1h + (size_t)(n * 128 + c0 + c) * 4096 + y * 64 + px0;
        *(u16x8*)dst = o0;
        *(u16x8*)(dst + 8) = o1;
    }
    {   // transposed outputs: raw x -> xpTh (interior), t2 -> t2T
        int p = t >> 2, cx0 = (t & 3) * 16;
        u16x8 r0, r1, s0, s1;
#pragma unroll
        for (int e = 0; e < 8; ++e) {
            float v0 = xs[cx0 + e][p];
            float v1 = xs[cx0 + 8 + e][p];
            r0[e] = f2bf(v0);
            r1[e] = f2bf(v1);
            s0[e] = f2bf(v0 + p1s[cx0 + e] * v0);
            s1[e] = f2bf(v1 + p1s[cx0 + 8 + e] * v1);
        }
        size_t baseT = ((size_t)n * 4096 + y * 64 + p) * 128 + c0 + cx0;
        *(u16x8*)(t2T + baseT) = s0;
        *(u16x8*)(t2T + baseT + 8) = s1;
        size_t baseP = ((size_t)n * 4752 + (y + 1) * 72 + p + 3) * 128 + c0 + cx0;
        *(u16x8*)(xpTh + baseP) = r0;
        *(u16x8*)(xpTh + baseP + 8) = r1;
    }
}

// ---- G[p][j] grouped 3x7 conv via MFMA, stage-once: Gh[n][32g+j][p] ----
__global__ __launch_bounds__(256) void g_mfma(const ushort_t* __restrict__ xpTh,
                                              const ushort_t* __restrict__ wfc,
                                              ushort_t* __restrict__ Gh) {
    __shared__ ushort_t Ts[6 * 72 * 32];        // 27,648 B
    const int p0 = blockIdx.x * 256;
    const int g  = blockIdx.y;
    const int n  = blockIdx.z;
    const int tid = threadIdx.x;
    const int lane = tid & 63, wid = tid >> 6;
    const int q = lane >> 4, fr = lane & 15;
    const int y0 = p0 >> 6;

    const ushort_t* src = xpTh + ((size_t)n * 4752 + y0 * 72) * 128 + g * 32;
    for (int flat = tid; flat < 1728; flat += 256) {
        int qq = flat & 3;
        int cc = (flat >> 2) % 72;
        int rr = (flat >> 2) / 72;
        u16x8 v = *(const u16x8*)(src + ((size_t)rr * 72 + cc) * 128 + qq * 8);
        *(u16x8*)&Ts[(rr * 72 + cc) * 32 + ((qq ^ ((cc >> 1) & 3)) * 8)] = v;
    }
    __syncthreads();

    const ushort_t* wbase = wfc + (size_t)g * 21 * 1024 + fr * 32 + q * 8;
    f32x4 acc[2][4] = {};
    for (int tap = 0; tap < 21; ++tap) {
        const int ki = tap / 7, kj = tap - ki * 7;
        s16x8 a[2], b[4];
#pragma unroll
        for (int i = 0; i < 2; ++i)
            a[i] = *(const s16x8*)(wbase + tap * 1024 + i * 16 * 32);
#pragma unroll
        for (int jj = 0; jj < 4; ++jj) {
            int col = wid * 64 + jj * 16 + fr;
            int rr = (col >> 6) + ki;
            int cc = (col & 63) + kj;
            b[jj] = *(const s16x8*)&Ts[(rr * 72 + cc) * 32 + ((q ^ ((cc >> 1) & 3)) * 8)];
        }
#pragma unroll
        for (int i = 0; i < 2; ++i)
#pragma unroll
            for (int jj = 0; jj < 4; ++jj)
                acc[i][jj] = __builtin_amdgcn_mfma_f32_16x16x32_bf16(a[i], b[jj], acc[i][jj], 0, 0, 0);
    }
#pragma unroll
    for (int i = 0; i < 2; ++i) {
        int row = i * 16 + q * 4;
#pragma unroll
        for (int jj = 0; jj < 4; ++jj) {
            int col = wid * 64 + jj * 16 + fr;
            ushort_t* dst = Gh + ((size_t)n * 128 + 32 * g + row) * 4096 + p0 + col;
#pragma unroll
            for (int reg = 0; reg < 4; ++reg)
                dst[(size_t)reg * 4096] = f2bf(acc[i][jj][reg]);
        }
    }
}

// ---- fused t7 (MFMA, relu-on-load) + t12 epilogue -> t12h (bf16) ----
__global__ __launch_bounds__(256) void t7t12_mfma(const ushort_t* __restrict__ p7h,
                                                  const ushort_t* __restrict__ xpTh,
                                                  const float* __restrict__ x,
                                                  ushort_t* __restrict__ t12h) {
    __shared__ ushort_t sh[16384];
    ushort_t* As = sh;
    ushort_t* Bs = sh + 8192;
    const int p0 = blockIdx.x * 128;
    const int n  = blockIdx.y;
    const int tid = threadIdx.x;
    const int lane = tid & 63, wid = tid >> 6;
    const int wr = wid >> 1, wc = wid & 1;

    const ushort_t* aPtr[4];
    const ushort_t* bPtr[4];
    int off[4];
#pragma unroll
    for (int r = 0; r < 4; ++r) {
        int slot = r * 256 + tid;
        int row = slot >> 3, ch = slot & 7;
        off[r] = (row * 8 + (ch ^ (row & 7))) * 8;
        aPtr[r] = p7h + row * 128 + ch * 8;
        int prow = p0 + row;
        int srow = ((prow >> 6) + 1) * 72 + (prow & 63) + 3;
        bPtr[r] = xpTh + ((size_t)n * 4752 + srow) * 128 + ch * 8;
    }
    const int q = lane >> 4, fr = lane & 15;
    int aRd[2][4], bRd[2][4];
#pragma unroll
    for (int i = 0; i < 4; ++i) {
        int ra = wr * 64 + i * 16 + fr;
        int rb = wc * 64 + i * 16 + fr;
#pragma unroll
        for (int ks = 0; ks < 2; ++ks) {
            aRd[ks][i] = (ra * 8 + ((ks * 4 + q) ^ (ra & 7))) * 8;
            bRd[ks][i] = (rb * 8 + ((ks * 4 + q) ^ (rb & 7))) * 8;
        }
    }
    f32x4 acc[4][4] = {};
    for (int t = 0; t < 2; ++t) {
        s16x8 av[4], bv[4];
#pragma unroll
        for (int r = 0; r < 4; ++r) {
            av[r] = *(const s16x8*)aPtr[r];
            bv[r] = relu8(*(const s16x8*)bPtr[r]);
            aPtr[r] += 64;
            bPtr[r] += 64;
        }
        __syncthreads();
#pragma unroll
        for (int r = 0; r < 4; ++r) {
            *(s16x8*)&As[off[r]] = av[r];
            *(s16x8*)&Bs[off[r]] = bv[r];
        }
        __syncthreads();
#pragma unroll
        for (int ks = 0; ks < 2; ++ks) {
            s16x8 a[4], b[4];
#pragma unroll
            for (int i = 0; i < 4; ++i) a[i] = *(const s16x8*)&As[aRd[ks][i]];
#pragma unroll
            for (int i = 0; i < 4; ++i) b[i] = *(const s16x8*)&Bs[bRd[ks][i]];
#pragma unroll
            for (int i = 0; i < 4; ++i)
#pragma unroll
                for (int j = 0; j < 4; ++j)
                    acc[i][j] = __builtin_amdgcn_mfma_f32_16x16x32_bf16(a[i], b[j], acc[i][j], 0, 0, 0);
        }
    }
    // t12 epilogue -> t12h
    ushort_t* Cs = sh;
    for (int pass = 0; pass < 2; ++pass) {
        __syncthreads();
        for (int i2 = tid; i2 < 4992; i2 += 256) ((uint_t*)Cs)[i2] = 0u;
        __syncthreads();
        if (wr == pass) {
#pragma unroll
            for (int i = 0; i < 4; ++i) {
                int row = i * 16 + q * 4;
#pragma unroll
                for (int j = 0; j < 4; ++j) {
                    int col = wc * 64 + j * 16 + fr;
                    int cbase = (col >> 6) * 78 + 6 + (col & 63);
#pragma unroll
                    for (int reg = 0; reg < 4; ++reg)
                        Cs[(row + reg) * 156 + cbase] = f2bf(acc[i][j][reg]);
                }
            }
        }
        __syncthreads();
        for (int rep = 0; rep < 32; ++rep) {
            int flat = rep * 256 + tid;
            int ol = flat >> 7;
            int pcol = flat & 127;
            int half = pcol >> 6, xx = pcol & 63;
            float s = 0.0f;
#pragma unroll
            for (int jj = 0; jj < 5; ++jj)
                s += bf2f(Cs[ol * 156 + half * 78 + xx + 3 * jj]);
            size_t oi = ((size_t)(n * 128 + pass * 64 + ol)) * 4096 + p0 + pcol;
            t12h[oi] = f2bf(x[oi] - 0.2f * s);
        }
    }
}

// ---- U partials (split-K=32): uparth[(n*32+ks)][c][j] bf16 ----
__global__ __launch_bounds__(256) void u_mfma(const ushort_t* __restrict__ t1h,
                                              const ushort_t* __restrict__ Gh,
                                              ushort_t* __restrict__ uparth) {
    __shared__ ushort_t As[8192];
    __shared__ ushort_t Bs[8192];
    const int ks = blockIdx.x;                  // 0..31
    const int n  = blockIdx.y;
    const int kbase = ks * 128;
    const int tid = threadIdx.x;
    const int lane = tid & 63, wid = tid >> 6;
    const int wr = wid >> 1, wc = wid & 1;
    const ushort_t* aPtr[4];
    const ushort_t* bPtr[4];
    int off[4];
#pragma unroll
    for (int r = 0; r < 4; ++r) {
        int slot = r * 256 + tid;
        int row = slot >> 3, ch = slot & 7;
        off[r] = (row * 8 + (ch ^ (row & 7))) * 8;
        aPtr[r] = t1h + (size_t)(n * 128 + row) * 4096 + kbase + ch * 8;
        bPtr[r] = Gh  + (size_t)(n * 128 + row) * 4096 + kbase + ch * 8;
    }
    const int q = lane >> 4, fr = lane & 15;
    int aRd[2][4], bRd[2][4];
#pragma unroll
    for (int i = 0; i < 4; ++i) {
        int ra = wr * 64 + i * 16 + fr;
        int rb = wc * 64 + i * 16 + fr;
#pragma unroll
        for (int ks2 = 0; ks2 < 2; ++ks2) {
            aRd[ks2][i] = (ra * 8 + ((ks2 * 4 + q) ^ (ra & 7))) * 8;
            bRd[ks2][i] = (rb * 8 + ((ks2 * 4 + q) ^ (rb & 7))) * 8;
        }
    }
    f32x4 acc[4][4] = {};
    for (int t = 0; t < 2; ++t) {
        s16x8 av[4], bv[4];
#pragma unroll
        for (int r = 0; r < 4; ++r) {
            av[r] = *(const s16x8*)aPtr[r];
            bv[r] = *(const s16x8*)bPtr[r];
            aPtr[r] += 64;
            bPtr[r] += 64;
        }
        __syncthreads();
#pragma unroll
        for (int r = 0; r < 4; ++r) {
            *(s16x8*)&As[off[r]] = av[r];
            *(s16x8*)&Bs[off[r]] = bv[r];
        }
        __syncthreads();
#pragma unroll
        for (int ks2 = 0; ks2 < 2; ++ks2) {
            s16x8 a[4], b[4];
#pragma unroll
            for (int i = 0; i < 4; ++i) a[i] = *(const s16x8*)&As[aRd[ks2][i]];
#pragma unroll
            for (int i = 0; i < 4; ++i) b[i] = *(const s16x8*)&Bs[bRd[ks2][i]];
#pragma unroll
            for (int i = 0; i < 4; ++i)
#pragma unroll
                for (int j = 0; j < 4; ++j)
                    acc[i][j] = __builtin_amdgcn_mfma_f32_16x16x32_bf16(a[i], b[j], acc[i][j], 0, 0, 0);
        }
    }
#pragma unroll
    for (int i = 0; i < 4; ++i) {
        int row = wr * 64 + i * 16 + q * 4;
#pragma unroll
        for (int j = 0; j < 4; ++j) {
            int col = wc * 64 + j * 16 + fr;
            ushort_t* dp = uparth + ((size_t)(n * 32 + ks) * 128 + row) * 128 + col;
#pragma unroll
            for (int reg = 0; reg < 4; ++reg)
                dp[(size_t)reg * 128] = f2bf(acc[i][j][reg]);
        }
    }
}

__global__ void ureduce_kernel(const ushort_t* __restrict__ uparth, ushort_t* __restrict__ Uh) {
    int idx = blockIdx.x * 256 + threadIdx.x;   // < 131072
    int n = idx >> 14, rc = idx & 16383;
    float s = 0.0f;
#pragma unroll
    for (int k = 0; k < 32; ++k) s += bf2f(uparth[(size_t)((n * 32 + k) << 14) + rc]);
    Uh[idx] = f2bf(s * 0.015625f);               // 1/64
}

// ---- t13: out = max(t12h, scale * Uh . t2T^T). grid (32 ptiles, 8 n) ----
__global__ __launch_bounds__(256) void t13_mfma(const ushort_t* __restrict__ Uh,
                                                const ushort_t* __restrict__ t2T,
                                                const ushort_t* __restrict__ t12h,
                                                float* __restrict__ out) {
    __shared__ ushort_t As[8192];
    __shared__ ushort_t Bs[8192];
    const int p0 = blockIdx.x * 128;
    const int n  = blockIdx.y;
    const int tid = threadIdx.x;
    const int lane = tid & 63, wid = tid >> 6;
    const int wr = wid >> 1, wc = wid & 1;
    const ushort_t* aPtr[4];
    const ushort_t* bPtr[4];
    int off[4];
#pragma unroll
    for (int r = 0; r < 4; ++r) {
        int slot = r * 256 + tid;
        int row = slot >> 3, ch = slot & 7;
        off[r] = (row * 8 + (ch ^ (row & 7))) * 8;
        aPtr[r] = Uh + ((size_t)n * 128 + row) * 128 + ch * 8;
        bPtr[r] = t2T + ((size_t)n * 4096 + p0 + row) * 128 + ch * 8;
    }
    const int q = lane >> 4, fr = lane & 15;
    int aRd[2][4], bRd[2][4];
#pragma unroll
    for (int i = 0; i < 4; ++i) {
        int ra = wr * 64 + i * 16 + fr;
        int rb = wc * 64 + i * 16 + fr;
#pragma unroll
        for (int ks = 0; ks < 2; ++ks) {
            aRd[ks][i] = (ra * 8 + ((ks * 4 + q) ^ (ra & 7))) * 8;
            bRd[ks][i] = (rb * 8 + ((ks * 4 + q) ^ (rb & 7))) * 8;
        }
    }
    f32x4 acc[4][4] = {};
    for (int t = 0; t < 2; ++t) {
        s16x8 av[4], bv[4];
#pragma unroll
        for (int r = 0; r < 4; ++r) {
            av[r] = *(const s16x8*)aPtr[r];
            bv[r] = *(const s16x8*)bPtr[r];
            aPtr[r] += 64;
            bPtr[r] += 64;
        }
        __syncthreads();
#pragma unroll
        for (int r = 0; r < 4; ++r) {
            *(s16x8*)&As[off[r]] = av[r];
            *(s16x8*)&Bs[off[r]] = bv[r];
        }
        __syncthreads();
#pragma unroll
        for (int ks = 0; ks < 2; ++ks) {
            s16x8 a[4], b[4];
#pragma unroll
            for (int i = 0; i < 4; ++i) a[i] = *(const s16x8*)&As[aRd[ks][i]];
#pragma unroll
            for (int i = 0; i < 4; ++i) b[i] = *(const s16x8*)&Bs[bRd[ks][i]];
#pragma unroll
            for (int i = 0; i < 4; ++i)
#pragma unroll
                for (int j = 0; j < 4; ++j)
                    acc[i][j] = __builtin_amdgcn_mfma_f32_16x16x32_bf16(a[i], b[j], acc[i][j], 0, 0, 0);
        }
    }
    const float scale = 0.0192879257f;   // 1/sqrt(2688)
#pragma unroll
    for (int i = 0; i < 4; ++i) {
        int row = wr * 64 + i * 16 + q * 4;
#pragma unroll
        for (int j = 0; j < 4; ++j) {
            int col = wc * 64 + j * 16 + fr;
#pragma unroll
            for (int reg = 0; reg < 4; ++reg) {
                size_t oi = ((size_t)(n * 128 + row + reg)) * 4096 + p0 + col;
                out[oi] = fmaxf(bf2f(t12h[oi]), acc[i][j][reg] * scale);
            }
        }
    }
}

extern "C" void kernel_launch(void* const* d_in, const int* in_sizes, int n_in,
                              void* d_out, int out_size, void* d_ws, size_t ws_size,
                              hipStream_t stream) {
    const float* x   = (const float*)d_in[0];
    const float* p1  = (const float*)d_in[1];
    const float* p7  = (const float*)d_in[2];
    const float* p10 = (const float*)d_in[3];
    float* out = (float*)d_out;

    ushort_t* t1h    = (ushort_t*)d_ws;         // 4,194,304
    ushort_t* t2T    = t1h + 4194304;           // 4,194,304
    ushort_t* xpTh   = t2T + 4194304;           // 4,866,048
    ushort_t* p7h    = xpTh + 4866048;          // 16,384
    ushort_t* Gh     = p7h + 16384;             // 4,194,304
    ushort_t* wfc    = Gh + 4194304;            // 86,016
    ushort_t* Uh     = wfc + 86016;             // 131,072
    ushort_t* t12h   = Uh + 131072;             // 4,194,304
    ushort_t* uparth = t12h + 4194304;          // 4,194,304

    prep_misc<<<728, 256, 0, stream>>>(p10, p7, xpTh, wfc, p7h);
    xtr_prep<<<dim3(64, 2, 8), 256, 0, stream>>>(x, p1, t1h, t2T, xpTh);
    g_mfma<<<dim3(16, 4, 8), 256, 0, stream>>>(xpTh, wfc, Gh);
    t7t12_mfma<<<dim3(32, 8), 256, 0, stream>>>(p7h, xpTh, x, t12h);
    u_mfma<<<dim3(32, 8), 256, 0, stream>>>(t1h, Gh, uparth);
    ureduce_kernel<<<512, 256, 0, stream>>>(uparth, Uh);
    t13_mfma<<<dim3(32, 8), 256, 0, stream>>>(Uh, t2T, t12h, out);
}

// Round 9
// 59.291 us; speedup vs baseline: 1.6055x; 1.0604x over previous
//
#include <hip/hip_runtime.h>
#include <hip/hip_bf16.h>

typedef unsigned short ushort_t;
typedef unsigned int uint_t;
typedef __attribute__((ext_vector_type(8))) short s16x8;
typedef __attribute__((ext_vector_type(4))) float f32x4;
typedef __attribute__((ext_vector_type(4))) ushort_t u16x4;
typedef __attribute__((ext_vector_type(8))) ushort_t u16x8;

__device__ __forceinline__ ushort_t f2bf(float f) {
    uint_t u = __float_as_uint(f);
    uint_t r = (u + 0x7FFFu + ((u >> 16) & 1u)) >> 16;
    return (ushort_t)r;
}
__device__ __forceinline__ float bf2f(ushort_t u) {
    return __uint_as_float(((uint_t)u) << 16);
}
__device__ __forceinline__ s16x8 relu8(s16x8 v) {
    s16x8 r;
#pragma unroll
    for (int e = 0; e < 8; ++e) { short xv = v[e]; r[e] = (xv < 0) ? (short)0 : xv; }
    return r;
}

// ---- merged misc prep: xpTh border zero + wfc gen + p7h cast ----
__global__ void prep_misc(const float* __restrict__ p10, const float* __restrict__ p7,
                          ushort_t* __restrict__ xpTh, ushort_t* __restrict__ wfc,
                          ushort_t* __restrict__ p7h) {
    int idx = blockIdx.x * 256 + threadIdx.x;
    if (idx < 83968) {
        int chunk = idx & 15;
        int rest  = idx >> 4;             // n*656 + s
        int n = rest / 656;
        int s = rest - n * 656;
        int yy, xx;
        if (s < 144) { yy = (s < 72) ? 0 : 65; xx = s % 72; }
        else { int s2 = s - 144; yy = (s2 >> 3) + 1; int k = s2 & 7; xx = (k < 3) ? k : k + 64; }
        u16x8 z = {};
        *(u16x8*)(xpTh + ((size_t)n * 4752 + yy * 72 + xx) * 128 + chunk * 8) = z;
    } else if (idx < 83968 + 86016) {
        int i = idx - 83968;
        int c32 = i & 31;
        int j = (i >> 5) & 31;
        int rest = i >> 10;               // g*21 + tap
        int tap = rest % 21, g = rest / 21;
        wfc[i] = f2bf(p10[((32 * g + c32) * 21 + tap) * 32 + j]);
    } else if (idx < 83968 + 86016 + 16384) {
        int i = idx - 83968 - 86016;
        p7h[i] = f2bf(p7[i]);
    }
}

// ---- prep: t1h[c][p], t2T[p][c], xpTh[s][c] interior ----
__global__ __launch_bounds__(256) void xtr_prep(const float* __restrict__ x,
                                                const float* __restrict__ p1,
                                                ushort_t* __restrict__ t1h,
                                                ushort_t* __restrict__ t2T,
                                                ushort_t* __restrict__ xpTh) {
    __shared__ float xs[64][65];
    __shared__ float p1s[64];
    const int y  = blockIdx.x;
    const int c0 = blockIdx.y * 64;
    const int n  = blockIdx.z;
    const int t  = threadIdx.x;
    if (t < 64) p1s[t] = p1[(c0 + t) * 64 + y];
#pragma unroll
    for (int cc = 0; cc < 4; ++cc) {
        int c = cc * 16 + (t >> 4);
        int px = (t & 15) * 4;
        float4 v = *(const float4*)(x + ((size_t)((n * 128 + c0 + c)) * 64 + y) * 64 + px);
        xs[c][px] = v.x; xs[c][px + 1] = v.y; xs[c][px + 2] = v.z; xs[c][px + 3] = v.w;
    }
    __syncthreads();
    {
        int c = t >> 2, px0 = (t & 3) * 16;
        float pv = p1s[c];
        u16x8 o0, o1;
#pragma unroll
        for (int e = 0; e < 8; ++e) {
            o0[e] = f2bf(pv * xs[c][px0 + e]);
            o1[e] = f2bf(pv * xs[c][px0 + 8 + e]);
        }
        ushort_t* dst = t1h + (size_t)(n * 128 + c0 + c) * 4096 + y * 64 + px0;
        *(u16x8*)dst = o0;
        *(u16x8*)(dst + 8) = o1;
    }
    {
        int p = t >> 2, cx0 = (t & 3) * 16;
        u16x8 r0, r1, s0, s1;
#pragma unroll
        for (int e = 0; e < 8; ++e) {
            float v0 = xs[cx0 + e][p];
            float v1 = xs[cx0 + 8 + e][p];
            r0[e] = f2bf(v0);
            r1[e] = f2bf(v1);
            s0[e] = f2bf(v0 + p1s[cx0 + e] * v0);
            s1[e] = f2bf(v1 + p1s[cx0 + 8 + e] * v1);
        }
        size_t baseT = ((size_t)n * 4096 + y * 64 + p) * 128 + c0 + cx0;
        *(u16x8*)(t2T + baseT) = s0;
        *(u16x8*)(t2T + baseT + 8) = s1;
        size_t baseP = ((size_t)n * 4752 + (y + 1) * 72 + p + 3) * 128 + c0 + cx0;
        *(u16x8*)(xpTh + baseP) = r0;
        *(u16x8*)(xpTh + baseP + 8) = r1;
    }
}

// ---- fused G-conv + U-partial: guf ----
// phase 1: G[32j x 256p] = grouped 3x7 conv (tap loop, Ts staging)
// phase 2: Upart^T[c][j] += sum_{p in tile} G[j][p] * t1h[c][p]
// grid (16 pt, 4 g, 8 n), 256 thr.
__global__ __launch_bounds__(256) void guf_mfma(const ushort_t* __restrict__ xpTh,
                                                const ushort_t* __restrict__ wfc,
                                                const ushort_t* __restrict__ t1h,
                                                ushort_t* __restrict__ uparth) {
    __shared__ ushort_t Ts[6 * 72 * 32];        // 27,648 B
    __shared__ ushort_t Gs[32 * 256];           // 16,384 B
    const int pt = blockIdx.x;
    const int p0 = pt * 256;
    const int g  = blockIdx.y;
    const int n  = blockIdx.z;
    const int tid = threadIdx.x;
    const int lane = tid & 63, wid = tid >> 6;
    const int q = lane >> 4, fr = lane & 15;
    const int y0 = p0 >> 6;

    // stage xpT slab
    const ushort_t* src = xpTh + ((size_t)n * 4752 + y0 * 72) * 128 + g * 32;
    for (int flat = tid; flat < 1728; flat += 256) {
        int qq = flat & 3;
        int cc = (flat >> 2) % 72;
        int rr = (flat >> 2) / 72;
        u16x8 v = *(const u16x8*)(src + ((size_t)rr * 72 + cc) * 128 + qq * 8);
        *(u16x8*)&Ts[(rr * 72 + cc) * 32 + ((qq ^ ((cc >> 1) & 3)) * 8)] = v;
    }
    __syncthreads();

    // phase 1: tap loop
    const ushort_t* wbase = wfc + (size_t)g * 21 * 1024 + fr * 32 + q * 8;
    f32x4 acc[2][4] = {};
    for (int tap = 0; tap < 21; ++tap) {
        const int ki = tap / 7, kj = tap - ki * 7;
        s16x8 a[2], b[4];
#pragma unroll
        for (int i = 0; i < 2; ++i)
            a[i] = *(const s16x8*)(wbase + tap * 1024 + i * 16 * 32);
#pragma unroll
        for (int jj = 0; jj < 4; ++jj) {
            int col = wid * 64 + jj * 16 + fr;
            int rr = (col >> 6) + ki;
            int cc = (col & 63) + kj;
            b[jj] = *(const s16x8*)&Ts[(rr * 72 + cc) * 32 + ((q ^ ((cc >> 1) & 3)) * 8)];
        }
#pragma unroll
        for (int i = 0; i < 2; ++i)
#pragma unroll
            for (int jj = 0; jj < 4; ++jj)
                acc[i][jj] = __builtin_amdgcn_mfma_f32_16x16x32_bf16(a[i], b[jj], acc[i][jj], 0, 0, 0);
    }
    // G -> Gs (bf16, chunk-swizzled rows): Gs[j*256 + ((p>>3)^(j&7))*8 + (p&7)]
#pragma unroll
    for (int i = 0; i < 2; ++i) {
#pragma unroll
        for (int jj = 0; jj < 4; ++jj) {
            int p = wid * 64 + jj * 16 + fr;
            int pc = p >> 3, pe = p & 7;
#pragma unroll
            for (int reg = 0; reg < 4; ++reg) {
                int j = i * 16 + q * 4 + reg;
                Gs[j * 256 + ((pc ^ (j & 7)) * 8) + pe] = f2bf(acc[i][jj][reg]);
            }
        }
    }
    __syncthreads();

    // phase 2: Upart^T = Gs . t1h^T over this p-tile (K=256)
    const ushort_t* t1base = t1h + (size_t)n * 128 * 4096 + p0;
    const int cb = wid * 32;
    f32x4 accu[2][2] = {};
    for (int kk = 0; kk < 8; ++kk) {
        s16x8 a[2], b[2];
#pragma unroll
        for (int i = 0; i < 2; ++i) {
            int j = i * 16 + fr;
            a[i] = *(const s16x8*)&Gs[j * 256 + (((kk * 4 + q) ^ (j & 7)) * 8)];
        }
#pragma unroll
        for (int l = 0; l < 2; ++l)
            b[l] = *(const s16x8*)(t1base + (size_t)(cb + l * 16 + fr) * 4096 + kk * 32 + q * 8);
#pragma unroll
        for (int i = 0; i < 2; ++i)
#pragma unroll
            for (int l = 0; l < 2; ++l)
                accu[i][l] = __builtin_amdgcn_mfma_f32_16x16x32_bf16(a[i], b[l], accu[i][l], 0, 0, 0);
    }
#pragma unroll
    for (int i = 0; i < 2; ++i) {
#pragma unroll
        for (int l = 0; l < 2; ++l) {
            int c = cb + l * 16 + fr;
            u16x4 o;
#pragma unroll
            for (int reg = 0; reg < 4; ++reg) o[reg] = f2bf(accu[i][l][reg]);
            *(u16x4*)&uparth[((size_t)(n * 16 + pt) * 128 + c) * 128 + g * 32 + i * 16 + q * 4] = o;
        }
    }
}

__global__ void ureduce_kernel(const ushort_t* __restrict__ uparth, ushort_t* __restrict__ Uh) {
    int idx = blockIdx.x * 256 + threadIdx.x;   // < 131072 : (n, c, j)
    int n = idx >> 14, rc = idx & 16383;
    float s = 0.0f;
#pragma unroll
    for (int k = 0; k < 16; ++k) s += bf2f(uparth[(size_t)((n * 16 + k) << 14) + rc]);
    Uh[idx] = f2bf(s * 0.015625f);               // 1/64
}

// ---- fused t7 (MFMA) + t12 epilogue -> t12h; x read from resident B-tile ----
// grid (32 ptiles, 8 n). B staged full-K (32KB), A (p7h) direct from global/L2.
__global__ __launch_bounds__(256) void t7t12_mfma(const ushort_t* __restrict__ p7h,
                                                  const ushort_t* __restrict__ xpTh,
                                                  ushort_t* __restrict__ t12h) {
    __shared__ ushort_t Bs[16384];              // 128 p-rows x 128 c (16 chunks, swz)
    __shared__ ushort_t Cs[9984];               // 64 x 156 halo tile
    const int p0 = blockIdx.x * 128;
    const int n  = blockIdx.y;
    const int tid = threadIdx.x;
    const int lane = tid & 63, wid = tid >> 6;
    const int wr = wid >> 1, wc = wid & 1;
    const int q = lane >> 4, fr = lane & 15;

    // stage B: 2048 chunks (row 0..127, ch 0..15), swz chunk' = ch ^ (row&15)
#pragma unroll
    for (int r = 0; r < 8; ++r) {
        int slot = r * 256 + tid;
        int row = slot >> 4, ch = slot & 15;
        int srow = ((p0 + row) >> 6) * 72 + 72 + ((p0 + row) & 63) + 3;
        u16x8 v = *(const u16x8*)(xpTh + ((size_t)n * 4752 + srow) * 128 + ch * 8);
        *(u16x8*)&Bs[(row * 16 + (ch ^ (row & 15))) * 8] = v;
    }
    __syncthreads();

    f32x4 acc[4][4] = {};
    for (int ks = 0; ks < 4; ++ks) {
        s16x8 a[4], b[4];
#pragma unroll
        for (int i = 0; i < 4; ++i) {
            int ra = wr * 64 + i * 16 + fr;
            a[i] = *(const s16x8*)(p7h + ra * 128 + ks * 32 + q * 8);
        }
#pragma unroll
        for (int i = 0; i < 4; ++i) {
            int rb = wc * 64 + i * 16 + fr;
            b[i] = relu8(*(const s16x8*)&Bs[(rb * 16 + ((ks * 4 + q) ^ (rb & 15))) * 8]);
        }
#pragma unroll
        for (int i = 0; i < 4; ++i)
#pragma unroll
            for (int j = 0; j < 4; ++j)
                acc[i][j] = __builtin_amdgcn_mfma_f32_16x16x32_bf16(a[i], b[j], acc[i][j], 0, 0, 0);
    }
    // epilogue: window-sum from Cs; x from Bs (raw bf16)
    for (int pass = 0; pass < 2; ++pass) {
        __syncthreads();
        for (int i2 = tid; i2 < 4992; i2 += 256) ((uint_t*)Cs)[i2] = 0u;
        __syncthreads();
        if (wr == pass) {
#pragma unroll
            for (int i = 0; i < 4; ++i) {
                int row = i * 16 + q * 4;
#pragma unroll
                for (int j = 0; j < 4; ++j) {
                    int col = wc * 64 + j * 16 + fr;
                    int cbase = (col >> 6) * 78 + 6 + (col & 63);
#pragma unroll
                    for (int reg = 0; reg < 4; ++reg)
                        Cs[(row + reg) * 156 + cbase] = f2bf(acc[i][j][reg]);
                }
            }
        }
        __syncthreads();
        for (int rep = 0; rep < 32; ++rep) {
            int flat = rep * 256 + tid;
            int ol = flat >> 7;                 // output channel (low 6 bits + pass)
            int pcol = flat & 127;              // spatial within tile
            int half = pcol >> 6, xx = pcol & 63;
            float s = 0.0f;
#pragma unroll
            for (int jj = 0; jj < 5; ++jj)
                s += bf2f(Cs[ol * 156 + half * 78 + xx + 3 * jj]);
            int c = pass * 64 + ol;
            float xv = bf2f(Bs[(pcol * 16 + ((c >> 3) ^ (pcol & 15))) * 8 + (c & 7)]);
            size_t oi = ((size_t)(n * 128 + c)) * 4096 + p0 + pcol;
            t12h[oi] = f2bf(xv - 0.2f * s);
        }
    }
}

// ---- t13: out = max(t12h, scale * Uh . t2T^T). grid (32 ptiles, 8 n) ----
__global__ __launch_bounds__(256) void t13_mfma(const ushort_t* __restrict__ Uh,
                                                const ushort_t* __restrict__ t2T,
                                                const ushort_t* __restrict__ t12h,
                                                float* __restrict__ out) {
    __shared__ ushort_t As[8192];
    __shared__ ushort_t Bs[8192];
    const int p0 = blockIdx.x * 128;
    const int n  = blockIdx.y;
    const int tid = threadIdx.x;
    const int lane = tid & 63, wid = tid >> 6;
    const int wr = wid >> 1, wc = wid & 1;
    const ushort_t* aPtr[4];
    const ushort_t* bPtr[4];
    int off[4];
#pragma unroll
    for (int r = 0; r < 4; ++r) {
        int slot = r * 256 + tid;
        int row = slot >> 3, ch = slot & 7;
        off[r] = (row * 8 + (ch ^ (row & 7))) * 8;
        aPtr[r] = Uh + ((size_t)n * 128 + row) * 128 + ch * 8;
        bPtr[r] = t2T + ((size_t)n * 4096 + p0 + row) * 128 + ch * 8;
    }
    const int q = lane >> 4, fr = lane & 15;
    int aRd[2][4], bRd[2][4];
#pragma unroll
    for (int i = 0; i < 4; ++i) {
        int ra = wr * 64 + i * 16 + fr;
        int rb = wc * 64 + i * 16 + fr;
#pragma unroll
        for (int ks = 0; ks < 2; ++ks) {
            aRd[ks][i] = (ra * 8 + ((ks * 4 + q) ^ (ra & 7))) * 8;
            bRd[ks][i] = (rb * 8 + ((ks * 4 + q) ^ (rb & 7))) * 8;
        }
    }
    f32x4 acc[4][4] = {};
    for (int t = 0; t < 2; ++t) {
        s16x8 av[4], bv[4];
#pragma unroll
        for (int r = 0; r < 4; ++r) {
            av[r] = *(const s16x8*)aPtr[r];
            bv[r] = *(const s16x8*)bPtr[r];
            aPtr[r] += 64;
            bPtr[r] += 64;
        }
        __syncthreads();
#pragma unroll
        for (int r = 0; r < 4; ++r) {
            *(s16x8*)&As[off[r]] = av[r];
            *(s16x8*)&Bs[off[r]] = bv[r];
        }
        __syncthreads();
#pragma unroll
        for (int ks = 0; ks < 2; ++ks) {
            s16x8 a[4], b[4];
#pragma unroll
            for (int i = 0; i < 4; ++i) a[i] = *(const s16x8*)&As[aRd[ks][i]];
#pragma unroll
            for (int i = 0; i < 4; ++i) b[i] = *(const s16x8*)&Bs[bRd[ks][i]];
#pragma unroll
            for (int i = 0; i < 4; ++i)
#pragma unroll
                for (int j = 0; j < 4; ++j)
                    acc[i][j] = __builtin_amdgcn_mfma_f32_16x16x32_bf16(a[i], b[j], acc[i][j], 0, 0, 0);
        }
    }
    const float scale = 0.0192879257f;   // 1/sqrt(2688)
#pragma unroll
    for (int i = 0; i < 4; ++i) {
        int row = wr * 64 + i * 16 + q * 4;
#pragma unroll
        for (int j = 0; j < 4; ++j) {
            int col = wc * 64 + j * 16 + fr;
#pragma unroll
            for (int reg = 0; reg < 4; ++reg) {
                size_t oi = ((size_t)(n * 128 + row + reg)) * 4096 + p0 + col;
                out[oi] = fmaxf(bf2f(t12h[oi]), acc[i][j][reg] * scale);
            }
        }
    }
}

extern "C" void kernel_launch(void* const* d_in, const int* in_sizes, int n_in,
                              void* d_out, int out_size, void* d_ws, size_t ws_size,
                              hipStream_t stream) {
    const float* x   = (const float*)d_in[0];
    const float* p1  = (const float*)d_in[1];
    const float* p7  = (const float*)d_in[2];
    const float* p10 = (const float*)d_in[3];
    float* out = (float*)d_out;

    ushort_t* t1h    = (ushort_t*)d_ws;         // 4,194,304
    ushort_t* t2T    = t1h + 4194304;           // 4,194,304
    ushort_t* xpTh   = t2T + 4194304;           // 4,866,048
    ushort_t* p7h    = xpTh + 4866048;          // 16,384
    ushort_t* wfc    = p7h + 16384;             // 86,016
    ushort_t* Uh     = wfc + 86016;             // 131,072
    ushort_t* t12h   = Uh + 131072;             // 4,194,304
    ushort_t* uparth = t12h + 4194304;          // 2,097,152

    prep_misc<<<728, 256, 0, stream>>>(p10, p7, xpTh, wfc, p7h);
    xtr_prep<<<dim3(64, 2, 8), 256, 0, stream>>>(x, p1, t1h, t2T, xpTh);
    guf_mfma<<<dim3(16, 4, 8), 256, 0, stream>>>(xpTh, wfc, t1h, uparth);
    t7t12_mfma<<<dim3(32, 8), 256, 0, stream>>>(p7h, xpTh, t12h);
    ureduce_kernel<<<512, 256, 0, stream>>>(uparth, Uh);
    t13_mfma<<<dim3(32, 8), 256, 0, stream>>>(Uh, t2T, t12h, out);
}

// Round 10
// 45.713 us; speedup vs baseline: 2.0823x; 1.2970x over previous
//
#include <hip/hip_runtime.h>
#include <hip/hip_bf16.h>

typedef unsigned short ushort_t;
typedef unsigned int uint_t;
typedef __attribute__((ext_vector_type(8))) short s16x8;
typedef __attribute__((ext_vector_type(4))) float f32x4;
typedef __attribute__((ext_vector_type(4))) ushort_t u16x4;
typedef __attribute__((ext_vector_type(8))) ushort_t u16x8;

__device__ __forceinline__ ushort_t f2bf(float f) {
    uint_t u = __float_as_uint(f);
    uint_t r = (u + 0x7FFFu + ((u >> 16) & 1u)) >> 16;
    return (ushort_t)r;
}
__device__ __forceinline__ float bf2f(ushort_t u) {
    return __uint_as_float(((uint_t)u) << 16);
}
__device__ __forceinline__ s16x8 relu8(s16x8 v) {
    s16x8 r;
#pragma unroll
    for (int e = 0; e < 8; ++e) { short xv = v[e]; r[e] = (xv < 0) ? (short)0 : xv; }
    return r;
}

// ---- prep_all: [0,1024) xtr tiles (t1h + xpTh interior); [1024,1752) misc ----
__global__ __launch_bounds__(256) void prep_all(const float* __restrict__ x,
                                                const float* __restrict__ p1,
                                                const float* __restrict__ p10,
                                                const float* __restrict__ p7,
                                                ushort_t* __restrict__ t1h,
                                                ushort_t* __restrict__ xpTh,
                                                ushort_t* __restrict__ wfc,
                                                ushort_t* __restrict__ p7h) {
    __shared__ float xs[64][65];
    __shared__ float p1s[64];
    const int b = blockIdx.x;
    const int t = threadIdx.x;
    if (b < 1024) {
        const int y  = b & 63;
        const int c0 = ((b >> 6) & 1) * 64;
        const int n  = b >> 7;
        if (t < 64) p1s[t] = p1[(c0 + t) * 64 + y];
#pragma unroll
        for (int cc = 0; cc < 4; ++cc) {
            int c = cc * 16 + (t >> 4);
            int px = (t & 15) * 4;
            float4 v = *(const float4*)(x + ((size_t)((n * 128 + c0 + c)) * 64 + y) * 64 + px);
            xs[c][px] = v.x; xs[c][px + 1] = v.y; xs[c][px + 2] = v.z; xs[c][px + 3] = v.w;
        }
        __syncthreads();
        {   // t1h natural layout
            int c = t >> 2, px0 = (t & 3) * 16;
            float pv = p1s[c];
            u16x8 o0, o1;
#pragma unroll
            for (int e = 0; e < 8; ++e) {
                o0[e] = f2bf(pv * xs[c][px0 + e]);
                o1[e] = f2bf(pv * xs[c][px0 + 8 + e]);
            }
            ushort_t* dst = t1h + (size_t)(n * 128 + c0 + c) * 4096 + y * 64 + px0;
            *(u16x8*)dst = o0;
            *(u16x8*)(dst + 8) = o1;
        }
        {   // transposed raw x -> xpTh interior
            int p = t >> 2, cx0 = (t & 3) * 16;
            u16x8 r0, r1;
#pragma unroll
            for (int e = 0; e < 8; ++e) {
                r0[e] = f2bf(xs[cx0 + e][p]);
                r1[e] = f2bf(xs[cx0 + 8 + e][p]);
            }
            size_t baseP = ((size_t)n * 4752 + (y + 1) * 72 + p + 3) * 128 + c0 + cx0;
            *(u16x8*)(xpTh + baseP) = r0;
            *(u16x8*)(xpTh + baseP + 8) = r1;
        }
    } else {
        int idx = (b - 1024) * 256 + t;         // < 186368
        if (idx < 83968) {
            int chunk = idx & 15;
            int rest  = idx >> 4;               // n*656 + s
            int n = rest / 656;
            int s = rest - n * 656;
            int yy, xx;
            if (s < 144) { yy = (s < 72) ? 0 : 65; xx = s % 72; }
            else { int s2 = s - 144; yy = (s2 >> 3) + 1; int k = s2 & 7; xx = (k < 3) ? k : k + 64; }
            u16x8 z = {};
            *(u16x8*)(xpTh + ((size_t)n * 4752 + yy * 72 + xx) * 128 + chunk * 8) = z;
        } else if (idx < 83968 + 86016) {
            int i = idx - 83968;
            int c32 = i & 31;
            int j = (i >> 5) & 31;
            int rest = i >> 10;                 // g*21 + tap
            int tap = rest % 21, g = rest / 21;
            wfc[i] = f2bf(p10[((32 * g + c32) * 21 + tap) * 32 + j]);
        } else if (idx < 83968 + 86016 + 16384) {
            int i = idx - 83968 - 86016;
            p7h[i] = f2bf(p7[i]);
        }
    }
}

// ---- fused G-conv + U-partial (unchanged from R9) ----
__global__ __launch_bounds__(256) void guf_mfma(const ushort_t* __restrict__ xpTh,
                                                const ushort_t* __restrict__ wfc,
                                                const ushort_t* __restrict__ t1h,
                                                ushort_t* __restrict__ uparth) {
    __shared__ ushort_t Ts[6 * 72 * 32];
    __shared__ ushort_t Gs[32 * 256];
    const int pt = blockIdx.x;
    const int p0 = pt * 256;
    const int g  = blockIdx.y;
    const int n  = blockIdx.z;
    const int tid = threadIdx.x;
    const int lane = tid & 63, wid = tid >> 6;
    const int q = lane >> 4, fr = lane & 15;
    const int y0 = p0 >> 6;

    const ushort_t* src = xpTh + ((size_t)n * 4752 + y0 * 72) * 128 + g * 32;
    for (int flat = tid; flat < 1728; flat += 256) {
        int qq = flat & 3;
        int cc = (flat >> 2) % 72;
        int rr = (flat >> 2) / 72;
        u16x8 v = *(const u16x8*)(src + ((size_t)rr * 72 + cc) * 128 + qq * 8);
        *(u16x8*)&Ts[(rr * 72 + cc) * 32 + ((qq ^ ((cc >> 1) & 3)) * 8)] = v;
    }
    __syncthreads();

    const ushort_t* wbase = wfc + (size_t)g * 21 * 1024 + fr * 32 + q * 8;
    f32x4 acc[2][4] = {};
    for (int tap = 0; tap < 21; ++tap) {
        const int ki = tap / 7, kj = tap - ki * 7;
        s16x8 a[2], b[4];
#pragma unroll
        for (int i = 0; i < 2; ++i)
            a[i] = *(const s16x8*)(wbase + tap * 1024 + i * 16 * 32);
#pragma unroll
        for (int jj = 0; jj < 4; ++jj) {
            int col = wid * 64 + jj * 16 + fr;
            int rr = (col >> 6) + ki;
            int cc = (col & 63) + kj;
            b[jj] = *(const s16x8*)&Ts[(rr * 72 + cc) * 32 + ((q ^ ((cc >> 1) & 3)) * 8)];
        }
#pragma unroll
        for (int i = 0; i < 2; ++i)
#pragma unroll
            for (int jj = 0; jj < 4; ++jj)
                acc[i][jj] = __builtin_amdgcn_mfma_f32_16x16x32_bf16(a[i], b[jj], acc[i][jj], 0, 0, 0);
    }
#pragma unroll
    for (int i = 0; i < 2; ++i) {
#pragma unroll
        for (int jj = 0; jj < 4; ++jj) {
            int p = wid * 64 + jj * 16 + fr;
            int pc = p >> 3, pe = p & 7;
#pragma unroll
            for (int reg = 0; reg < 4; ++reg) {
                int j = i * 16 + q * 4 + reg;
                Gs[j * 256 + ((pc ^ (j & 7)) * 8) + pe] = f2bf(acc[i][jj][reg]);
            }
        }
    }
    __syncthreads();

    const ushort_t* t1base = t1h + (size_t)n * 128 * 4096 + p0;
    const int cb = wid * 32;
    f32x4 accu[2][2] = {};
    for (int kk = 0; kk < 8; ++kk) {
        s16x8 a[2], b[2];
#pragma unroll
        for (int i = 0; i < 2; ++i) {
            int j = i * 16 + fr;
            a[i] = *(const s16x8*)&Gs[j * 256 + (((kk * 4 + q) ^ (j & 7)) * 8)];
        }
#pragma unroll
        for (int l = 0; l < 2; ++l)
            b[l] = *(const s16x8*)(t1base + (size_t)(cb + l * 16 + fr) * 4096 + kk * 32 + q * 8);
#pragma unroll
        for (int i = 0; i < 2; ++i)
#pragma unroll
            for (int l = 0; l < 2; ++l)
                accu[i][l] = __builtin_amdgcn_mfma_f32_16x16x32_bf16(a[i], b[l], accu[i][l], 0, 0, 0);
    }
#pragma unroll
    for (int i = 0; i < 2; ++i) {
#pragma unroll
        for (int l = 0; l < 2; ++l) {
            int c = cb + l * 16 + fr;
            u16x4 o;
#pragma unroll
            for (int reg = 0; reg < 4; ++reg) o[reg] = f2bf(accu[i][l][reg]);
            *(u16x4*)&uparth[((size_t)(n * 16 + pt) * 128 + c) * 128 + g * 32 + i * 16 + q * 4] = o;
        }
    }
}

__global__ void ureduce_kernel(const ushort_t* __restrict__ uparth, ushort_t* __restrict__ Uh) {
    int idx = blockIdx.x * 256 + threadIdx.x;   // < 131072 : (n, c, j)
    int n = idx >> 14, rc = idx & 16383;
    float s = 0.0f;
#pragma unroll
    for (int k = 0; k < 16; ++k) s += bf2f(uparth[(size_t)((n * 16 + k) << 14) + rc]);
    Uh[idx] = f2bf(s * 0.015625f);               // 1/64
}

// ---- fully fused output: t7 MFMA + t12 + t13 MFMA + max. grid (64 y, 8 n) ----
// Tile: M=128, N=64 (one y row), K=128. Bs raw x^T is reused for both GEMMs
// (relu at read for t7; in-place (1+p1) rescale for t13's t2 operand).
__global__ __launch_bounds__(256) void outf_mfma(const ushort_t* __restrict__ p7h,
                                                 const ushort_t* __restrict__ xpTh,
                                                 const ushort_t* __restrict__ Uh,
                                                 const float* __restrict__ p1,
                                                 float* __restrict__ out) {
    __shared__ ushort_t Bs[8192];               // 64p x 128c, swz 16 KB
    __shared__ ushort_t Cs[9984];               // 128 x 78 halo  19.9 KB
    __shared__ ushort_t T12s[8192];             // 128c x 64p     16 KB
    __shared__ float p1s[128];
    const int y = blockIdx.x;
    const int n = blockIdx.y;
    const int tid = threadIdx.x;
    const int lane = tid & 63, w = tid >> 6;
    const int q = lane >> 4, fr = lane & 15;

    if (tid < 128) p1s[tid] = p1[tid * 64 + y];
    // stage Bs: 1024 chunks; swz chunk' = ch ^ (row&15)
    int adS[4], chS[4];
#pragma unroll
    for (int it = 0; it < 4; ++it) {
        int slot = it * 256 + tid;
        int row = slot >> 4, ch = slot & 15;
        chS[it] = ch;
        adS[it] = (row * 16 + (ch ^ (row & 15))) * 8;
        u16x8 v = *(const u16x8*)(xpTh + ((size_t)n * 4752 + (y + 1) * 72 + 3 + row) * 128 + ch * 8);
        *(u16x8*)&Bs[adS[it]] = v;
    }
    __syncthreads();

    // phase A: t7 = p7h . relu(Bs)
    f32x4 acc[2][4] = {};
    for (int ks = 0; ks < 4; ++ks) {
        s16x8 a[2], b[4];
#pragma unroll
        for (int i = 0; i < 2; ++i)
            a[i] = *(const s16x8*)(p7h + (w * 32 + i * 16 + fr) * 128 + ks * 32 + q * 8);
#pragma unroll
        for (int jj = 0; jj < 4; ++jj) {
            int rb = jj * 16 + fr;
            b[jj] = relu8(*(const s16x8*)&Bs[(rb * 16 + ((ks * 4 + q) ^ (rb & 15))) * 8]);
        }
#pragma unroll
        for (int i = 0; i < 2; ++i)
#pragma unroll
            for (int jj = 0; jj < 4; ++jj)
                acc[i][jj] = __builtin_amdgcn_mfma_f32_16x16x32_bf16(a[i], b[jj], acc[i][jj], 0, 0, 0);
    }
    // Cs: zero, then write t7 tile at halo offset
    for (int i2 = tid; i2 < 4992; i2 += 256) ((uint_t*)Cs)[i2] = 0u;
    __syncthreads();
#pragma unroll
    for (int i = 0; i < 2; ++i)
#pragma unroll
        for (int jj = 0; jj < 4; ++jj) {
            int col = jj * 16 + fr;
#pragma unroll
            for (int reg = 0; reg < 4; ++reg) {
                int row = w * 32 + i * 16 + q * 4 + reg;
                Cs[row * 78 + 6 + col] = f2bf(acc[i][jj][reg]);
            }
        }
    __syncthreads();
    // t12 = x - 0.2*window5(t7)  -> T12s
    for (int rep = 0; rep < 32; ++rep) {
        int flat = rep * 256 + tid;
        int c = flat >> 6, xx = flat & 63;
        float s = 0.0f;
#pragma unroll
        for (int jj = 0; jj < 5; ++jj)
            s += bf2f(Cs[c * 78 + xx + 3 * jj]);
        float xv = bf2f(Bs[(xx * 16 + ((c >> 3) ^ (xx & 15))) * 8 + (c & 7)]);
        T12s[flat] = f2bf(xv - 0.2f * s);
    }
    __syncthreads();
    // rescale Bs in place: t2^T = x^T * (1 + p1[c,y])
#pragma unroll
    for (int it = 0; it < 4; ++it) {
        u16x8 v = *(u16x8*)&Bs[adS[it]];
        u16x8 o;
#pragma unroll
        for (int e = 0; e < 8; ++e)
            o[e] = f2bf(bf2f(v[e]) * (1.0f + p1s[chS[it] * 8 + e]));
        *(u16x8*)&Bs[adS[it]] = o;
    }
    __syncthreads();
    // phase B: t13 = Uh . t2^T
    f32x4 acc2[2][4] = {};
    for (int ks = 0; ks < 4; ++ks) {
        s16x8 a[2], b[4];
#pragma unroll
        for (int i = 0; i < 2; ++i)
            a[i] = *(const s16x8*)(Uh + ((size_t)(n * 128 + w * 32 + i * 16 + fr)) * 128 + ks * 32 + q * 8);
#pragma unroll
        for (int jj = 0; jj < 4; ++jj) {
            int rb = jj * 16 + fr;
            b[jj] = *(const s16x8*)&Bs[(rb * 16 + ((ks * 4 + q) ^ (rb & 15))) * 8];
        }
#pragma unroll
        for (int i = 0; i < 2; ++i)
#pragma unroll
            for (int jj = 0; jj < 4; ++jj)
                acc2[i][jj] = __builtin_amdgcn_mfma_f32_16x16x32_bf16(a[i], b[jj], acc2[i][jj], 0, 0, 0);
    }
    // epilogue: out = max(t12, scale * t13)
    const float scale = 0.0192879257f;   // 1/sqrt(2688)
#pragma unroll
    for (int i = 0; i < 2; ++i)
#pragma unroll
        for (int jj = 0; jj < 4; ++jj) {
            int col = jj * 16 + fr;
#pragma unroll
            for (int reg = 0; reg < 4; ++reg) {
                int row = w * 32 + i * 16 + q * 4 + reg;
                size_t oi = ((size_t)(n * 128 + row)) * 4096 + y * 64 + col;
                out[oi] = fmaxf(bf2f(T12s[row * 64 + col]), acc2[i][jj][reg] * scale);
            }
        }
}

extern "C" void kernel_launch(void* const* d_in, const int* in_sizes, int n_in,
                              void* d_out, int out_size, void* d_ws, size_t ws_size,
                              hipStream_t stream) {
    const float* x   = (const float*)d_in[0];
    const float* p1  = (const float*)d_in[1];
    const float* p7  = (const float*)d_in[2];
    const float* p10 = (const float*)d_in[3];
    float* out = (float*)d_out;

    ushort_t* t1h    = (ushort_t*)d_ws;         // 4,194,304
    ushort_t* xpTh   = t1h + 4194304;           // 4,866,048
    ushort_t* p7h    = xpTh + 4866048;          // 16,384
    ushort_t* wfc    = p7h + 16384;             // 86,016
    ushort_t* Uh     = wfc + 86016;             // 131,072
    ushort_t* uparth = Uh + 131072;             // 2,097,152

    prep_all<<<1752, 256, 0, stream>>>(x, p1, p10, p7, t1h, xpTh, wfc, p7h);
    guf_mfma<<<dim3(16, 4, 8), 256, 0, stream>>>(xpTh, wfc, t1h, uparth);
    ureduce_kernel<<<512, 256, 0, stream>>>(uparth, Uh);
    outf_mfma<<<dim3(64, 8), 256, 0, stream>>>(p7h, xpTh, Uh, p1, out);
}